// Round 8
// baseline (1499.316 us; speedup 1.0000x reference)
//
#include <hip/hip_runtime.h>
#include <hip/hip_bf16.h>

#define BB 8
#define HH 256
#define WW 256
#define HW 65536

typedef __attribute__((ext_vector_type(8))) short bf16x8;
typedef __attribute__((ext_vector_type(4))) float f32x4;
typedef __attribute__((ext_vector_type(8))) unsigned short u16x8;
#define MFMA16(a, b, c) __builtin_amdgcn_mfma_f32_16x16x32_bf16(a, b, c, 0, 0, 0)

__device__ __forceinline__ ushort f2bf(float f) {
  union { float f; uint32_t u; } c; c.f = f;
  uint32_t r = (c.u + 0x7fffu + ((c.u >> 16) & 1u)) >> 16;
  return (ushort)r;
}

// ---------------- workspace layout (bytes) ----------------
#define OFF_XG    0            // xg unique-maps bf16: 8*24*65536*2 = 25,165,824
#define OFF_PP    25165824     // pooled partials f32: 2048*1152*4  = 9,437,184 (ends 34,603,008)
#define OFF_BP    34603008     // Bp bf16 (K'=512 layout): 16*128*32*2 = 131,072 (ends 34,734,080 < 69MB)
#define OFF_XGN   69206016     // xg NHWC bf16 (72ch padded):   = 75,497,472
#define OFF_OUT1  144703488    // out1 f32: 8*65536*4           = 2,097,152
#define OFF_KERN  146837504    // kern f32: 8*1323*4            = 42,336 (+pad)
#define OFF_BW    146880000    // Bw bf16: [cc(2)][t9][o80][32]; alloc 138,240
#define OFF_BWZ   147018240    // BwZ bf16: 2*80*32*2           = 10,240
#define OFF_BIAS  147126784    // bias_tot f32: 80*4 (+pad)
#define OFF_TB    147127296    // TB f32: 66*9*4 (+pad)
#define OFF_T     147129856    // T f32: 66*81*4 (+pad)

// ---------------------------------------------------------------------------
// prepA: T, TB, Bw (gauss-chunk weights), Bp (pred1 weights, K'=u*44+vv*4+c)
// ---------------------------------------------------------------------------
__global__ __launch_bounds__(256) void k_prepA(const float* __restrict__ fuw,
                                               const float* __restrict__ trw,
                                               const float* __restrict__ trb,
                                               const float* __restrict__ p1w,
                                               float* __restrict__ T,
                                               float* __restrict__ TB,
                                               ushort* __restrict__ Bw,
                                               ushort* __restrict__ Bp) {
  int i = blockIdx.x * 256 + threadIdx.x;
  if (i < 5346) {  // T
    int o = i / 81, a = (i / 9) % 9, s = i % 9;
    float acc = 0.f;
    for (int cp = 0; cp < 66; ++cp)
      acc += fuw[(o * 132 + 66 + cp) * 9 + a] *
             (trw[(cp * 3) * 9 + s] + trw[(cp * 3 + 1) * 9 + s] + trw[(cp * 3 + 2) * 9 + s]);
    T[i] = acc; return;
  }
  i -= 5346;
  if (i < 594) {  // TB
    int o = i / 9, a = i % 9;
    float acc = 0.f;
    for (int cp = 0; cp < 66; ++cp) acc += trb[cp] * fuw[(o * 132 + 66 + cp) * 9 + a];
    TB[i] = acc; return;
  }
  i -= 594;
  if (i < 2 * 9 * 80 * 32) {  // Bw
    int cc = i / 23040, t = (i / 2560) % 9, o = (i / 32) % 80, kl = i & 31;
    int c = cc * 32 + kl;
    Bw[i] = (o < 66) ? f2bf(fuw[(o * 132 + c) * 9 + t]) : 0;
    return;
  }
  i -= 2 * 9 * 80 * 32;
  if (i < 16 * 128 * 32) {  // Bp (K' = u*44 + vv*4 + c; c==3 and k'>=484 are pad)
    int kc = i / 4096, o = (i / 32) % 128, kl = i & 31;
    int k = kc * 32 + kl;
    float v = 0.f;
    if (k < 484) { int u = k / 44, r2 = k % 44, vv = r2 / 4, c = r2 & 3;
                   if (c < 3) v = p1w[(o * 3 + c) * 121 + u * 11 + vv]; }
    Bp[i] = f2bf(v);
    return;
  }
}

__device__ __forceinline__ float W5val(int o, int d, const float* T) {
  int dy = d / 5, dx = d % 5;
  float acc = 0.f;
  for (int ua = 0; ua < 3; ++ua) {
    int us = dy - ua; if (us < 0 || us > 2) continue;
    for (int va = 0; va < 3; ++va) {
      int vs = dx - va; if (vs < 0 || vs > 2) continue;
      acc += T[(o * 9 + ua * 3 + va) * 9 + us * 3 + vs];
    }
  }
  return acc;
}

// prepB: BwZ (z-chunk weights: xg ch64/65 taps + composed 5x5 W5) and bias_tot
__global__ __launch_bounds__(256) void k_prepB(const float* __restrict__ fuw,
                                               const float* __restrict__ fub,
                                               const float* __restrict__ T,
                                               const float* __restrict__ TB,
                                               ushort* __restrict__ BwZ,
                                               float* __restrict__ bias_tot) {
  int i = blockIdx.x * 256 + threadIdx.x;
  if (i < 5120) {
    int zc = i / 2560, o = (i / 32) % 80, s = i & 31;
    float v = 0.f;
    if (o < 66) {
      if (zc == 0) {
        if (s < 18) { int ch = 64 + s / 9, a = s % 9; v = fuw[(o * 132 + ch) * 9 + a]; }
        else        { v = W5val(o, s - 18, T); }
      } else {
        if (s < 11) v = W5val(o, 14 + s, T);
      }
    }
    BwZ[i] = f2bf(v); return;
  }
  i -= 5120;
  if (i < 80) {
    float v = 0.f;
    if (i < 66) { v = fub[i]; for (int a = 0; a < 9; ++a) v += TB[i * 9 + a]; }
    bias_tot[i] = v;
  }
}

// ---------------------------------------------------------------------------
// Kernel A: x_gauss — 24 unique (g, j) maps; k_tr fans out to 66 channels.
// ---------------------------------------------------------------------------
template <int KS>
__device__ __forceinline__ void xg_conv(const float* __restrict__ xt,
                                        const float* __restrict__ wgp,
                                        float* a, int r, int wq) {
  constexpr int P0 = (21 - KS) / 2;
  constexpr int Q0 = P0 & ~3;
  constexpr int D0 = P0 - Q0;
  constexpr int NL = ((P0 + KS + 6) >> 2) - (P0 >> 2) + 1;
#pragma unroll 1
  for (int kh = P0; kh < P0 + KS; ++kh) {
    float rx[NL * 4];
    const int F0 = (r + kh) * 320 + 8 * wq + Q0;
#pragma unroll
    for (int i = 0; i < NL; ++i) {
      int Fi = F0 + 4 * i;
      *(float4*)(rx + 4 * i) = *(const float4*)(xt + (Fi ^ (((Fi >> 5) & 1) << 2)));
    }
    const float* wr = wgp + kh * 21 + P0;  // wave-uniform -> scalar loads
#pragma unroll
    for (int t = 0; t < KS; ++t) {
      float wv = wr[t];
#pragma unroll
      for (int u = 0; u < 8; ++u) a[u] += wv * rx[D0 + t + u];
    }
  }
}

__global__ __launch_bounds__(256, 4) void k_xgauss(const float* __restrict__ x,
                                                   const float* __restrict__ wg,
                                                   __hip_bfloat16* __restrict__ xg) {
  const int bu = blockIdx.z;
  const int b = bu / 24, u = bu % 24;
  const int g = u >> 3;              // input channel
  const int j = (u & 7) + 7 * g;     // kernel index (o/3)
  const int h0 = blockIdx.y * 8;
  __shared__ __align__(16) float xt[28 * 320];
  const float* xp = x + (b * 3 + g) * HW;
  for (int e = threadIdx.x; e < 28 * 320; e += 256) {
    int row = e / 320, col = e % 320;
    int gy = h0 + row - 10, gx = col - 10;
    float v = (gy >= 0 && gy < HH && gx >= 0 && gx < WW) ? xp[gy * WW + gx] : 0.f;
    xt[e ^ (((e >> 5) & 1) << 2)] = v;
  }
  __syncthreads();
  int i_ = j - 1;
  int im = (i_ - 1 > 0) ? (i_ - 1) : 0;
  const int ks = (j == 0) ? 1 : 3 + 2 * (im >> 1);
  const int wq = threadIdx.x & 31, r = threadIdx.x >> 5;
  const float* wgp = wg + (3 * j) * 441;
  float a[8] = {0.f, 0.f, 0.f, 0.f, 0.f, 0.f, 0.f, 0.f};
  switch (ks) {
    case 1:  xg_conv<1>(xt, wgp, a, r, wq); break;
    case 3:  xg_conv<3>(xt, wgp, a, r, wq); break;
    case 5:  xg_conv<5>(xt, wgp, a, r, wq); break;
    case 7:  xg_conv<7>(xt, wgp, a, r, wq); break;
    case 9:  xg_conv<9>(xt, wgp, a, r, wq); break;
    case 11: xg_conv<11>(xt, wgp, a, r, wq); break;
    case 13: xg_conv<13>(xt, wgp, a, r, wq); break;
    case 15: xg_conv<15>(xt, wgp, a, r, wq); break;
    case 17: xg_conv<17>(xt, wgp, a, r, wq); break;
    case 19: xg_conv<19>(xt, wgp, a, r, wq); break;
    default: xg_conv<21>(xt, wgp, a, r, wq); break;
  }
  u16x8 ov;
#pragma unroll
  for (int k = 0; k < 8; ++k) ov[k] = f2bf(a[k]);
  int oidx = (bu * HW) + (h0 + r) * WW + 8 * wq;
  *(u16x8*)((ushort*)xg + oidx) = ov;
}

// ---------------------------------------------------------------------------
// Transpose xg unique-maps -> NHWC (72-ch padded), fanning 24 maps out to 66
// channels: channel c reads unique map uid = c/3 + c/22.
// ---------------------------------------------------------------------------
__global__ __launch_bounds__(256) void k_tr(const ushort* __restrict__ xg,
                                            ushort* __restrict__ xgn) {
  __shared__ ushort ls[64 * 72];
  int p0 = blockIdx.x * 64;
  int b = p0 >> 16, sp = p0 & 65535;
  for (int e = threadIdx.x; e < 72 * 64; e += 256) {
    int c = e >> 6, i = e & 63;
    int uc = c / 3 + c / 22;
    ls[i * 72 + c] = (c < 66) ? xg[(size_t)(b * 24 + uc) * HW + sp + i] : (ushort)0;
  }
  __syncthreads();
  for (int e = threadIdx.x; e < 576; e += 256) {
    *(float4*)(xgn + (size_t)p0 * 72 + e * 8) = *(const float4*)(ls + e * 8);
  }
}

// ---------------------------------------------------------------------------
// Predictor stage 1 — RESTRUCTURED for occupancy + vector gathers.
//  * xt2 float4/pixel (c=3 pad 0); K' = u*44+vv*4+c (484 -> 16 K-chunks).
//    A-octet = 2 aligned ds_read_b128 (crossings split 4|4; u=(s*745)>>15
//    exact for s<512). Pad region of xt2 zeroed so padded k' reads 0.
//  * 1024 threads, 16 waves, 1 m-row/wave: acc[8] = 32 regs ->
//    __launch_bounds__(1024,4) = 4 waves/SIMD (2x r7's occupancy; r7 was
//    latency-bound at 2 waves/SIMD with acc[4][8]=128 regs).
//  * ps split 4-way by q -> pool atomics conflict-free (q was 4-way aliased).
// ---------------------------------------------------------------------------
__global__ __launch_bounds__(1024, 4) void k_pmm(const float* __restrict__ x,
                                                 const ushort* __restrict__ Bp,
                                                 const float* __restrict__ p1b,
                                                 float* __restrict__ pp) {
  __shared__ __align__(16) float xt2[3840];   // 26*26*4 = 2704 used + pad zeros
  __shared__ float ps[4 * 1152];
  const int b = blockIdx.z, h0 = blockIdx.y * 16, w0 = blockIdx.x * 16;
  const int tid = threadIdx.x, wave = tid >> 6, lane = tid & 63;
  const int m = lane & 15, q = lane >> 4;
  for (int e = tid; e < 4608; e += 1024) ps[e] = 0.f;
  if (tid < 676) {
    int py = tid / 26, pxc = tid % 26, gy = h0 - 2 + py, gx = w0 - 2 + pxc;
    float4 v = make_float4(0.f, 0.f, 0.f, 0.f);
    if (gy >= 0 && gy < HH && gx >= 0 && gx < WW) {
      const float* xb = x + b * 3 * HW + gy * WW + gx;
      v.x = xb[0]; v.y = xb[HW]; v.z = xb[2 * HW];
    }
    *(float4*)(xt2 + tid * 4) = v;
  }
  for (int e = tid; e < 1136; e += 1024) xt2[2704 + e] = 0.f;
  f32x4 acc[8];
#pragma unroll
  for (int n = 0; n < 8; ++n) acc[n] = (f32x4){0.f, 0.f, 0.f, 0.f};
  __syncthreads();   // xt2 ready; no further barriers until epilogue
  const int q8 = q * 8;
  const float* afb = xt2 + (wave * 26 + m) * 4;   // 16B-aligned per-lane base
#pragma unroll
  for (int kc = 0; kc < 16; ++kc) {
    const int s = kc * 32 + q8;
    const int u = (s * 745) >> 15;       // s/44, exact for s<512
    const int rem = s - 44 * u;
    const int a0 = s + 60 * u;           // off'(s): row u jump = +60 floats
    const int a1 = a0 + ((rem == 40) ? 64 : 4);
    float4 lo = *(const float4*)(afb + a0);
    float4 hi = *(const float4*)(afb + a1);
    union { ushort us[8]; bf16x8 v; } af;
    af.us[0] = f2bf(lo.x); af.us[1] = f2bf(lo.y);
    af.us[2] = f2bf(lo.z); af.us[3] = f2bf(lo.w);
    af.us[4] = f2bf(hi.x); af.us[5] = f2bf(hi.y);
    af.us[6] = f2bf(hi.z); af.us[7] = f2bf(hi.w);
    bf16x8 bf[8];
#pragma unroll
    for (int nt = 0; nt < 8; ++nt)
      bf[nt] = *(const bf16x8*)(Bp + ((kc * 128 + nt * 16 + m) * 32 + q8));
#pragma unroll
    for (int nt = 0; nt < 8; ++nt)
      acc[nt] = MFMA16(af.v, bf[nt], acc[nt]);
  }
  // epilogue: bias + leaky + pool into per-q ps copy (conflict-free atomics)
  float bv[8];
#pragma unroll
  for (int nt = 0; nt < 8; ++nt) bv[nt] = p1b[nt * 16 + m];
  const int h = h0 + wave;
  float* psq = ps + q * 1152;
  if (h < 250) {
    bool h0m = h < 84, h1m = (h >= 83 && h < 167), h2m = h >= 166;
#pragma unroll
    for (int r = 0; r < 4; ++r) {
      int w = w0 + (q << 2) + r;
      if (w >= 250) continue;
      bool w0m = w < 84, w1m = (w >= 83 && w < 167), w2m = w >= 166;
#pragma unroll
      for (int nt = 0; nt < 8; ++nt) {
        int o = (nt << 4) + m;
        float vz = acc[nt][r] + bv[nt];
        vz = vz >= 0.f ? vz : 0.2f * vz;
        if (h0m) { if (w0m) atomicAdd(&psq[o], vz);        if (w1m) atomicAdd(&psq[128 + o], vz);
                   if (w2m) atomicAdd(&psq[256 + o], vz); }
        if (h1m) { if (w0m) atomicAdd(&psq[384 + o], vz);  if (w1m) atomicAdd(&psq[512 + o], vz);
                   if (w2m) atomicAdd(&psq[640 + o], vz); }
        if (h2m) { if (w0m) atomicAdd(&psq[768 + o], vz);  if (w1m) atomicAdd(&psq[896 + o], vz);
                   if (w2m) atomicAdd(&psq[1024 + o], vz); }
      }
    }
  }
  __syncthreads();
  // reduce 4 q-copies + coalesced per-tile partial store ([k*9+p] layout)
  const int tile = blockIdx.y * 16 + blockIdx.x;
  float* dst = pp + (size_t)(b * 256 + tile) * 1152;
  for (int e = tid; e < 1152; e += 1024) {
    int idx = (e % 9) * 128 + (e / 9);
    dst[e] = ps[idx] + ps[1152 + idx] + ps[2304 + idx] + ps[3456 + idx];
  }
}

// ---------------------------------------------------------------------------
// Predictor tail: reduce the 256 per-tile partials, then fc chain + softmax.
// ---------------------------------------------------------------------------
__global__ __launch_bounds__(256) void k_pred2(const float* __restrict__ pp,
                                               const float* __restrict__ p2w,
                                               const float* __restrict__ p3w,
                                               float* __restrict__ kernw) {
  const int b = blockIdx.x;
  const int tid = threadIdx.x;
  __shared__ float hin[1152];
  __shared__ float h2p[1323];
  __shared__ float h3l[1323];
  __shared__ float mx[3], sm[3];
  for (int e = tid; e < 1152; e += 256) {
    float s = 0.f;
    const float* qp = pp + (size_t)b * 256 * 1152 + e;
#pragma unroll 4
    for (int t = 0; t < 256; ++t) s += qp[t * 1152];
    hin[e] = s * (1.f / 7056.f);
  }
  __syncthreads();
  for (int c = tid; c < 441; c += 256) {
    float z[9] = {0.f,0.f,0.f,0.f,0.f,0.f,0.f,0.f,0.f};
    const float* wr = p2w + c * 128;
    for (int k = 0; k < 128; k++) {
      float wv = wr[k];
      const float* hp = &hin[k * 9];
#pragma unroll
      for (int p = 0; p < 9; p++) z[p] += wv * hp[p];
    }
#pragma unroll
    for (int i = 0; i < 3; i++) {
      float s = 0.f;
#pragma unroll
      for (int jj = 0; jj < 3; jj++) {
        float zz = z[i * 3 + jj];
        s += (zz >= 0.f) ? zz : 0.2f * zz;
      }
      h2p[c * 3 + i] = s * (1.f / 3.f);
    }
  }
  __syncthreads();
  for (int c = tid; c < 441; c += 256) {
    float a0 = 0.f, a1 = 0.f, a2 = 0.f;
    const float* wr = p3w + c * 441;
    for (int k = 0; k < 441; k++) {
      float wv = wr[k];
      a0 += wv * h2p[k * 3];
      a1 += wv * h2p[k * 3 + 1];
      a2 += wv * h2p[k * 3 + 2];
    }
    h3l[c * 3] = a0; h3l[c * 3 + 1] = a1; h3l[c * 3 + 2] = a2;
  }
  __syncthreads();
  if (tid < 3) {
    float mxv = -1e30f;
    for (int c = 0; c < 441; c++) mxv = fmaxf(mxv, h3l[c * 3 + tid]);
    float s = 0.f;
    for (int c = 0; c < 441; c++) s += expf(h3l[c * 3 + tid] - mxv);
    mx[tid] = mxv; sm[tid] = 1.f / s;
  }
  __syncthreads();
  for (int f = tid; f < 1323; f += 256) {
    int i = f % 3;
    kernw[b * 1323 + f] = expf(h3l[f] - mx[i]) * sm[i];
  }
}

// ---------------------------------------------------------------------------
// Kernel D: per-sample dynamic conv (unchanged)
// ---------------------------------------------------------------------------
__global__ __launch_bounds__(256) void k_dyn(const float* __restrict__ x,
                                             const float* __restrict__ kernw,
                                             float* __restrict__ out1) {
  const int b = blockIdx.z;
  const int h0 = blockIdx.y * 16, w0 = blockIdx.x * 64;
  __shared__ float kl[1323];
  __shared__ float xt[3 * 36 * 84];
  for (int e = threadIdx.x; e < 1323; e += 256) kl[e] = kernw[b * 1323 + e];
  for (int e = threadIdx.x; e < 3 * 36 * 84; e += 256) {
    int ci = e / 3024, rem = e % 3024;
    int ty = rem / 84, tx = rem % 84;
    int gy = h0 + ty - 10, gx = w0 + tx - 10;
    xt[e] = (gy >= 0 && gy < HH && gx >= 0 && gx < WW)
                ? x[(b * 3 + ci) * HW + gy * WW + gx] : 0.f;
  }
  __syncthreads();
  const int wq = threadIdx.x & 15, r = threadIdx.x >> 4;
  float a0 = 0.f, a1 = 0.f, a2 = 0.f, a3 = 0.f;
  for (int ci = 0; ci < 3; ci++) {
    for (int kh = 0; kh < 21; kh++) {
      float rx[24];
      const float4* rp = (const float4*)&xt[ci * 3024 + (r + kh) * 84 + 4 * wq];
      float4* rv = (float4*)rx;
#pragma unroll
      for (int i = 0; i < 6; i++) rv[i] = rp[i];
      const float* wr = &kl[ci * 441 + kh * 21];
#pragma unroll
      for (int kw = 0; kw < 21; kw++) {
        float wv = wr[kw];
        a0 += wv * rx[kw];     a1 += wv * rx[kw + 1];
        a2 += wv * rx[kw + 2]; a3 += wv * rx[kw + 3];
      }
    }
  }
  int idx = b * HW + (h0 + r) * WW + w0 + 4 * wq;
  *(float4*)&out1[idx] = make_float4(a0, a1, a2, a3);
}

// ---------------------------------------------------------------------------
// Kernel E: ax_out (unchanged)
// ---------------------------------------------------------------------------
__global__ __launch_bounds__(256) void k_ax(const float* __restrict__ x,
                                            const float* __restrict__ csw,
                                            const float* __restrict__ csb,
                                            float* __restrict__ out2) {
  int idx = blockIdx.x * 256 + threadIdx.x;
  if (idx >= BB * 3 * HW) return;
  int w = idx & 255, h = (idx >> 8) & 255;
  int oc = (idx >> 16) % 3, b = idx / (3 * HW);
  float acc = csb[oc];
  for (int ic = 0; ic < 3; ic++) {
    const float* xc = x + (b * 3 + ic) * HW;
    const float* wp = csw + (oc * 3 + ic) * 9;
#pragma unroll
    for (int u = 0; u < 3; u++) {
      int iy = h + u - 1;
      if (iy < 0 || iy >= HH) continue;
#pragma unroll
      for (int v = 0; v < 3; v++) {
        int ix = w + v - 1;
        if (ix >= 0 && ix < WW) acc += xc[iy * WW + ix] * wp[u * 3 + v];
      }
    }
  }
  out2[idx] = acc;
}

// ---------------------------------------------------------------------------
// Fused conv as MFMA implicit GEMM (unchanged)
// ---------------------------------------------------------------------------
__global__ __launch_bounds__(256, 3) void k_fmma(const ushort* __restrict__ xgn,
                                                 const float* __restrict__ out1,
                                                 const ushort* __restrict__ Bw,
                                                 const ushort* __restrict__ BwZ,
                                                 const float* __restrict__ bias_tot,
                                                 float* __restrict__ outf) {
  __shared__ __align__(16) char smem[40080];
  ushort* xs  = (ushort*)smem;               // 18*18*32 bf16 = 20736
  float*  o1s = (float*)(smem + 20736);      // 20*20 f32     = 1600
  ushort* xs2 = (ushort*)(smem + 22336);     // 18*18*2 bf16  = 1296
  ushort* az  = (ushort*)(smem + 23632);     // 256*32 bf16   = 16384
  float*  st  = (float*)(smem + 23632);      // 16*257 f32    = 16448 (aliases az)
  const int b = blockIdx.z, h0 = blockIdx.y * 16, w0 = blockIdx.x * 16;
  const int tid = threadIdx.x, wave = tid >> 6, lane = tid & 63;
  const int m = lane & 15, q = lane >> 4;
  f32x4 acc[4][5];
#pragma unroll
  for (int a = 0; a < 4; ++a)
#pragma unroll
    for (int n = 0; n < 5; ++n) acc[a][n] = (f32x4){0.f, 0.f, 0.f, 0.f};

  for (int cc = 0; cc < 2; ++cc) {
    __syncthreads();
    for (int e = tid; e < 1296; e += 256) {
      int u = e & 3, p = e >> 2, py = p / 18, px = p % 18;
      int gy = h0 - 1 + py, gx = w0 - 1 + px;
      float4 v = make_float4(0.f, 0.f, 0.f, 0.f);
      if (gy >= 0 && gy < HH && gx >= 0 && gx < WW)
        v = *(const float4*)(xgn + (size_t)(b * HW + gy * WW + gx) * 72 + cc * 32 + u * 8);
      *(float4*)(xs + p * 32 + u * 8) = v;
    }
    __syncthreads();
#pragma unroll
    for (int t = 0; t < 9; ++t) {
      const int u = t / 3, v = t % 3;
      bf16x8 bf[5];
#pragma unroll
      for (int nt = 0; nt < 5; ++nt)
        bf[nt] = *(const bf16x8*)(Bw + (((cc * 9 + t) * 80 + nt * 16 + m) * 32 + q * 8));
#pragma unroll
      for (int mt = 0; mt < 4; ++mt) {
        int row = (wave << 2) + mt;
        bf16x8 af = *(const bf16x8*)(xs + ((row + u) * 18 + m + v) * 32 + q * 8);
#pragma unroll
        for (int nt = 0; nt < 5; ++nt)
          acc[mt][nt] = MFMA16(af, bf[nt], acc[mt][nt]);
      }
    }
  }
  __syncthreads();
  for (int e = tid; e < 324; e += 256) {
    int py = e / 18, px = e % 18, gy = h0 - 1 + py, gx = w0 - 1 + px;
    uint32_t v = 0;
    if (gy >= 0 && gy < HH && gx >= 0 && gx < WW)
      v = *(const uint32_t*)(xgn + (size_t)(b * HW + gy * WW + gx) * 72 + 64);
    *(uint32_t*)(xs2 + e * 2) = v;
  }
  for (int e = tid; e < 400; e += 256) {
    int py = e / 20, px = e % 20, gy = h0 - 2 + py, gx = w0 - 2 + px;
    o1s[e] = (gy >= 0 && gy < HH && gx >= 0 && gx < WW) ? out1[b * HW + gy * WW + gx] : 0.f;
  }
  __syncthreads();
  const int bpy = tid >> 4, bpx = tid & 15;
#pragma unroll
  for (int zc = 0; zc < 2; ++zc) {
    union { ushort us[32]; float4 f4[4]; } vals;
    if (zc == 0) {
#pragma unroll
      for (int s = 0; s < 18; ++s) {
        int ch = s / 9, a = s % 9, u = a / 3, v = a % 3;
        vals.us[s] = xs2[((bpy + u) * 18 + bpx + v) * 2 + ch];
      }
#pragma unroll
      for (int d = 0; d < 14; ++d)
        vals.us[18 + d] = f2bf(o1s[(bpy + d / 5) * 20 + bpx + d % 5]);
    } else {
#pragma unroll
      for (int s = 0; s < 11; ++s) {
        int d = 14 + s;
        vals.us[s] = f2bf(o1s[(bpy + d / 5) * 20 + bpx + d % 5]);
      }
#pragma unroll
      for (int s = 11; s < 32; ++s) vals.us[s] = 0;
    }
    __syncthreads();
#pragma unroll
    for (int u = 0; u < 4; ++u)
      *(float4*)(az + tid * 32 + ((u ^ (tid & 3)) << 3)) = vals.f4[u];
    __syncthreads();
    bf16x8 bf[5];
#pragma unroll
    for (int nt = 0; nt < 5; ++nt)
      bf[nt] = *(const bf16x8*)(BwZ + ((zc * 80 + nt * 16 + m) * 32 + q * 8));
#pragma unroll
    for (int mt = 0; mt < 4; ++mt) {
      int px = (((wave << 2) + mt) << 4) + m;
      bf16x8 af = *(const bf16x8*)(az + px * 32 + ((q ^ (px & 3)) << 3));
#pragma unroll
      for (int nt = 0; nt < 5; ++nt)
        acc[mt][nt] = MFMA16(af, bf[nt], acc[mt][nt]);
    }
  }
#pragma unroll 1
  for (int nt = 0; nt < 5; ++nt) {
    __syncthreads();
#pragma unroll
    for (int mt = 0; mt < 4; ++mt) {
      int pxb = (((wave << 2) + mt) << 4);
#pragma unroll
      for (int r = 0; r < 4; ++r)
        st[m * 257 + pxb + q * 4 + r] = acc[mt][nt][r];
    }
    __syncthreads();
#pragma unroll
    for (int kk = 0; kk < 16; ++kk) {
      int o = nt * 16 + kk;
      if (o < 66) {
        float bvv = bias_tot[o];
        outf[((b * 66 + o) * HH + h0 + (tid >> 4)) * WW + w0 + (tid & 15)] =
            st[kk * 257 + tid] + bvv;
      }
    }
  }
}

// ---------------------------------------------------------------------------
// Border fixup (unchanged)
// ---------------------------------------------------------------------------
__global__ __launch_bounds__(256) void k_fix(const float* __restrict__ out1,
                                             const float* __restrict__ T,
                                             const float* __restrict__ TB,
                                             float* __restrict__ outf) {
  int idx = blockIdx.x * 256 + threadIdx.x;
  if (idx >= 8 * 1020 * 66) return;
  int b = idx / (1020 * 66);
  int rem = idx % (1020 * 66);
  int pi = rem / 66, o = rem % 66;
  int ph, pw;
  if (pi < 256)      { ph = 0;        pw = pi; }
  else if (pi < 512) { ph = 255;      pw = pi - 256; }
  else if (pi < 766) { ph = pi - 511; pw = 0; }
  else               { ph = pi - 765; pw = 255; }
  float corr = 0.f;
#pragma unroll
  for (int a = 0; a < 9; ++a) {
    int ua = a / 3, va = a % 3;
    int qh = ph + ua - 1, qw = pw + va - 1;
    if (qh >= 0 && qh < HH && qw >= 0 && qw < WW) continue;
    float s = TB[o * 9 + a];
#pragma unroll
    for (int t2 = 0; t2 < 9; ++t2) {
      int rh = qh + t2 / 3 - 1, rw = qw + t2 % 3 - 1;
      if (rh >= 0 && rh < HH && rw >= 0 && rw < WW)
        s += out1[b * HW + rh * WW + rw] * T[(o * 9 + a) * 9 + t2];
    }
    corr += s;
  }
  outf[((b * 66 + o) * HH + ph) * WW + pw] -= corr;
}

// ---------------------------------------------------------------------------
extern "C" void kernel_launch(void* const* d_in, const int* in_sizes, int n_in,
                              void* d_out, int out_size, void* d_ws, size_t ws_size,
                              hipStream_t stream) {
  const float* x   = (const float*)d_in[0];
  const float* wg  = (const float*)d_in[1];
  const float* p1w = (const float*)d_in[2];
  const float* p1b = (const float*)d_in[3];
  const float* p2w = (const float*)d_in[4];
  const float* p3w = (const float*)d_in[5];
  const float* csw = (const float*)d_in[6];
  const float* csb = (const float*)d_in[7];
  const float* trw = (const float*)d_in[8];
  const float* trb = (const float*)d_in[9];
  const float* fuw = (const float*)d_in[10];
  const float* fub = (const float*)d_in[11];
  float* outf = (float*)d_out;                 // fused: 8*66*256*256
  float* out2 = outf + 34603008;               // ax_out: 8*3*256*256
  char* ws = (char*)d_ws;
  __hip_bfloat16* xg = (__hip_bfloat16*)(ws + OFF_XG);
  float* pp      = (float*)(ws + OFF_PP);
  ushort* Bp     = (ushort*)(ws + OFF_BP);
  ushort* xgn    = (ushort*)(ws + OFF_XGN);
  float* out1    = (float*)(ws + OFF_OUT1);
  float* kernw   = (float*)(ws + OFF_KERN);
  ushort* Bw     = (ushort*)(ws + OFF_BW);
  ushort* BwZ    = (ushort*)(ws + OFF_BWZ);
  float* biasT   = (float*)(ws + OFF_BIAS);
  float* TBp     = (float*)(ws + OFF_TB);
  float* Tp      = (float*)(ws + OFF_T);

  hipLaunchKernelGGL(k_prepA, dim3(460), dim3(256), 0, stream,
                     fuw, trw, trb, p1w, Tp, TBp, Bw, Bp);
  hipLaunchKernelGGL(k_prepB, dim3(21), dim3(256), 0, stream,
                     fuw, fub, Tp, TBp, BwZ, biasT);
  hipLaunchKernelGGL(k_xgauss, dim3(1, 32, 8 * 24), dim3(256), 0, stream, x, wg, xg);
  hipLaunchKernelGGL(k_tr, dim3(8192), dim3(256), 0, stream, (const ushort*)xg, xgn);
  hipLaunchKernelGGL(k_pmm, dim3(16, 16, 8), dim3(1024), 0, stream, x, Bp, p1b, pp);
  hipLaunchKernelGGL(k_pred2, dim3(8), dim3(256), 0, stream, pp, p2w, p3w, kernw);
  hipLaunchKernelGGL(k_dyn, dim3(4, 16, 8), dim3(256), 0, stream, x, kernw, out1);
  hipLaunchKernelGGL(k_fmma, dim3(16, 16, 8), dim3(256), 0, stream,
                     xgn, out1, Bw, BwZ, biasT, outf);
  hipLaunchKernelGGL(k_fix, dim3(2104), dim3(256), 0, stream, out1, Tp, TBp, outf);
  hipLaunchKernelGGL(k_ax, dim3(6144), dim3(256), 0, stream, x, csw, csb, out2);
}

// Round 9
// 1344.673 us; speedup vs baseline: 1.1150x; 1.1150x over previous
//
#include <hip/hip_runtime.h>
#include <hip/hip_bf16.h>

#define BB 8
#define HH 256
#define WW 256
#define HW 65536

typedef __attribute__((ext_vector_type(8))) short bf16x8;
typedef __attribute__((ext_vector_type(4))) float f32x4;
typedef __attribute__((ext_vector_type(8))) unsigned short u16x8;
#define MFMA16(a, b, c) __builtin_amdgcn_mfma_f32_16x16x32_bf16(a, b, c, 0, 0, 0)

__device__ __forceinline__ ushort f2bf(float f) {
  union { float f; uint32_t u; } c; c.f = f;
  uint32_t r = (c.u + 0x7fffu + ((c.u >> 16) & 1u)) >> 16;
  return (ushort)r;
}

// ---------------- workspace layout (bytes) ----------------
#define OFF_XG    0            // xg unique-maps bf16: 8*24*65536*2 = 25,165,824
#define OFF_PP    25165824     // pooled partials f32: 2048*1152*4  = 9,437,184 (ends 34,603,008)
#define OFF_BP    34603008     // Bp bf16 (K'=512 layout): 16*128*32*2 = 131,072 (ends 34,734,080 < 69MB)
#define OFF_XGN   69206016     // xg NHWC bf16 (72ch padded):   = 75,497,472
#define OFF_OUT1  144703488    // out1 f32: 8*65536*4           = 2,097,152
#define OFF_KERN  146837504    // kern f32: 8*1323*4            = 42,336 (+pad)
#define OFF_BW    146880000    // Bw bf16: [cc(2)][t9][o80][32]; alloc 138,240
#define OFF_BWZ   147018240    // BwZ bf16: 2*80*32*2           = 10,240
#define OFF_BIAS  147126784    // bias_tot f32: 80*4 (+pad)
#define OFF_TB    147127296    // TB f32: 66*9*4 (+pad)
#define OFF_T     147129856    // T f32: 66*81*4 (+pad)

// ---------------------------------------------------------------------------
// prepA: T, TB, Bw (gauss-chunk weights), Bp (pred1 weights, K'=u*44+vv*4+c)
// ---------------------------------------------------------------------------
__global__ __launch_bounds__(256) void k_prepA(const float* __restrict__ fuw,
                                               const float* __restrict__ trw,
                                               const float* __restrict__ trb,
                                               const float* __restrict__ p1w,
                                               float* __restrict__ T,
                                               float* __restrict__ TB,
                                               ushort* __restrict__ Bw,
                                               ushort* __restrict__ Bp) {
  int i = blockIdx.x * 256 + threadIdx.x;
  if (i < 5346) {  // T
    int o = i / 81, a = (i / 9) % 9, s = i % 9;
    float acc = 0.f;
    for (int cp = 0; cp < 66; ++cp)
      acc += fuw[(o * 132 + 66 + cp) * 9 + a] *
             (trw[(cp * 3) * 9 + s] + trw[(cp * 3 + 1) * 9 + s] + trw[(cp * 3 + 2) * 9 + s]);
    T[i] = acc; return;
  }
  i -= 5346;
  if (i < 594) {  // TB
    int o = i / 9, a = i % 9;
    float acc = 0.f;
    for (int cp = 0; cp < 66; ++cp) acc += trb[cp] * fuw[(o * 132 + 66 + cp) * 9 + a];
    TB[i] = acc; return;
  }
  i -= 594;
  if (i < 2 * 9 * 80 * 32) {  // Bw
    int cc = i / 23040, t = (i / 2560) % 9, o = (i / 32) % 80, kl = i & 31;
    int c = cc * 32 + kl;
    Bw[i] = (o < 66) ? f2bf(fuw[(o * 132 + c) * 9 + t]) : 0;
    return;
  }
  i -= 2 * 9 * 80 * 32;
  if (i < 16 * 128 * 32) {  // Bp (K' = u*44 + vv*4 + c; c==3 and k'>=484 are pad)
    int kc = i / 4096, o = (i / 32) % 128, kl = i & 31;
    int k = kc * 32 + kl;
    float v = 0.f;
    if (k < 484) { int u = k / 44, r2 = k % 44, vv = r2 / 4, c = r2 & 3;
                   if (c < 3) v = p1w[(o * 3 + c) * 121 + u * 11 + vv]; }
    Bp[i] = f2bf(v);
    return;
  }
}

__device__ __forceinline__ float W5val(int o, int d, const float* T) {
  int dy = d / 5, dx = d % 5;
  float acc = 0.f;
  for (int ua = 0; ua < 3; ++ua) {
    int us = dy - ua; if (us < 0 || us > 2) continue;
    for (int va = 0; va < 3; ++va) {
      int vs = dx - va; if (vs < 0 || vs > 2) continue;
      acc += T[(o * 9 + ua * 3 + va) * 9 + us * 3 + vs];
    }
  }
  return acc;
}

// prepB: BwZ (z-chunk weights: xg ch64/65 taps + composed 5x5 W5) and bias_tot
__global__ __launch_bounds__(256) void k_prepB(const float* __restrict__ fuw,
                                               const float* __restrict__ fub,
                                               const float* __restrict__ T,
                                               const float* __restrict__ TB,
                                               ushort* __restrict__ BwZ,
                                               float* __restrict__ bias_tot) {
  int i = blockIdx.x * 256 + threadIdx.x;
  if (i < 5120) {
    int zc = i / 2560, o = (i / 32) % 80, s = i & 31;
    float v = 0.f;
    if (o < 66) {
      if (zc == 0) {
        if (s < 18) { int ch = 64 + s / 9, a = s % 9; v = fuw[(o * 132 + ch) * 9 + a]; }
        else        { v = W5val(o, s - 18, T); }
      } else {
        if (s < 11) v = W5val(o, 14 + s, T);
      }
    }
    BwZ[i] = f2bf(v); return;
  }
  i -= 5120;
  if (i < 80) {
    float v = 0.f;
    if (i < 66) { v = fub[i]; for (int a = 0; a < 9; ++a) v += TB[i * 9 + a]; }
    bias_tot[i] = v;
  }
}

// ---------------------------------------------------------------------------
// Kernel A: x_gauss — 24 unique (g, j) maps; k_tr fans out to 66 channels.
// ---------------------------------------------------------------------------
template <int KS>
__device__ __forceinline__ void xg_conv(const float* __restrict__ xt,
                                        const float* __restrict__ wgp,
                                        float* a, int r, int wq) {
  constexpr int P0 = (21 - KS) / 2;
  constexpr int Q0 = P0 & ~3;
  constexpr int D0 = P0 - Q0;
  constexpr int NL = ((P0 + KS + 6) >> 2) - (P0 >> 2) + 1;
#pragma unroll 1
  for (int kh = P0; kh < P0 + KS; ++kh) {
    float rx[NL * 4];
    const int F0 = (r + kh) * 320 + 8 * wq + Q0;
#pragma unroll
    for (int i = 0; i < NL; ++i) {
      int Fi = F0 + 4 * i;
      *(float4*)(rx + 4 * i) = *(const float4*)(xt + (Fi ^ (((Fi >> 5) & 1) << 2)));
    }
    const float* wr = wgp + kh * 21 + P0;  // wave-uniform -> scalar loads
#pragma unroll
    for (int t = 0; t < KS; ++t) {
      float wv = wr[t];
#pragma unroll
      for (int u = 0; u < 8; ++u) a[u] += wv * rx[D0 + t + u];
    }
  }
}

__global__ __launch_bounds__(256, 4) void k_xgauss(const float* __restrict__ x,
                                                   const float* __restrict__ wg,
                                                   __hip_bfloat16* __restrict__ xg) {
  const int bu = blockIdx.z;
  const int b = bu / 24, u = bu % 24;
  const int g = u >> 3;              // input channel
  const int j = (u & 7) + 7 * g;     // kernel index (o/3)
  const int h0 = blockIdx.y * 8;
  __shared__ __align__(16) float xt[28 * 320];
  const float* xp = x + (b * 3 + g) * HW;
  for (int e = threadIdx.x; e < 28 * 320; e += 256) {
    int row = e / 320, col = e % 320;
    int gy = h0 + row - 10, gx = col - 10;
    float v = (gy >= 0 && gy < HH && gx >= 0 && gx < WW) ? xp[gy * WW + gx] : 0.f;
    xt[e ^ (((e >> 5) & 1) << 2)] = v;
  }
  __syncthreads();
  int i_ = j - 1;
  int im = (i_ - 1 > 0) ? (i_ - 1) : 0;
  const int ks = (j == 0) ? 1 : 3 + 2 * (im >> 1);
  const int wq = threadIdx.x & 31, r = threadIdx.x >> 5;
  const float* wgp = wg + (3 * j) * 441;
  float a[8] = {0.f, 0.f, 0.f, 0.f, 0.f, 0.f, 0.f, 0.f};
  switch (ks) {
    case 1:  xg_conv<1>(xt, wgp, a, r, wq); break;
    case 3:  xg_conv<3>(xt, wgp, a, r, wq); break;
    case 5:  xg_conv<5>(xt, wgp, a, r, wq); break;
    case 7:  xg_conv<7>(xt, wgp, a, r, wq); break;
    case 9:  xg_conv<9>(xt, wgp, a, r, wq); break;
    case 11: xg_conv<11>(xt, wgp, a, r, wq); break;
    case 13: xg_conv<13>(xt, wgp, a, r, wq); break;
    case 15: xg_conv<15>(xt, wgp, a, r, wq); break;
    case 17: xg_conv<17>(xt, wgp, a, r, wq); break;
    case 19: xg_conv<19>(xt, wgp, a, r, wq); break;
    default: xg_conv<21>(xt, wgp, a, r, wq); break;
  }
  u16x8 ov;
#pragma unroll
  for (int k = 0; k < 8; ++k) ov[k] = f2bf(a[k]);
  int oidx = (bu * HW) + (h0 + r) * WW + 8 * wq;
  *(u16x8*)((ushort*)xg + oidx) = ov;
}

// ---------------------------------------------------------------------------
// Transpose xg unique-maps -> NHWC (72-ch padded), fanning 24 maps out to 66
// channels: channel c reads unique map uid = c/3 + c/22.
// ---------------------------------------------------------------------------
__global__ __launch_bounds__(256) void k_tr(const ushort* __restrict__ xg,
                                            ushort* __restrict__ xgn) {
  __shared__ ushort ls[64 * 72];
  int p0 = blockIdx.x * 64;
  int b = p0 >> 16, sp = p0 & 65535;
  for (int e = threadIdx.x; e < 72 * 64; e += 256) {
    int c = e >> 6, i = e & 63;
    int uc = c / 3 + c / 22;
    ls[i * 72 + c] = (c < 66) ? xg[(size_t)(b * 24 + uc) * HW + sp + i] : (ushort)0;
  }
  __syncthreads();
  for (int e = threadIdx.x; e < 576; e += 256) {
    *(float4*)(xgn + (size_t)p0 * 72 + e * 8) = *(const float4*)(ls + e * 8);
  }
}

// ---------------------------------------------------------------------------
// Predictor stage 1 — bf16 NHWC-padded LDS tile, k_fmma-style A-path.
//  * xtb[26*26][4] bf16 (c=3 pad 0), converted ONCE at staging. K' =
//    u*44+vv*4+c (484 pad to 512, 16 chunks). A-octet = 2 pixels x 4ch =
//    two aligned ds_read_b64 — no in-loop f2bf, no scalar gather (r7/r8
//    showed that dependent gather+convert chain starved MFMA at any
//    occupancy: MfmaUtil pinned ~4.7%).
//  * r7 shell: 256 thr, 4 waves, acc[4][8], barrier-free K-loop.
//  * ps split 4-way by q -> conflict-free pool atomics (r8).
//  * __launch_bounds__(256,2) REQUIRED (r3: tighter bound spills acc).
// ---------------------------------------------------------------------------
__global__ __launch_bounds__(256, 2) void k_pmm(const float* __restrict__ x,
                                                const ushort* __restrict__ Bp,
                                                const float* __restrict__ p1b,
                                                float* __restrict__ pp) {
  __shared__ __align__(16) ushort xtb[2880];   // 2704 data + zero pad
  __shared__ float ps[4 * 1152];
  const int b = blockIdx.z, h0 = blockIdx.y * 16, w0 = blockIdx.x * 16;
  const int tid = threadIdx.x, wave = tid >> 6, lane = tid & 63;
  const int m = lane & 15, q = lane >> 4;
  for (int e = tid; e < 4608; e += 256) ps[e] = 0.f;
  for (int e = tid; e < 676; e += 256) {
    int py = e / 26, pxc = e % 26, gy = h0 - 2 + py, gx = w0 - 2 + pxc;
    ushort4 v = make_ushort4(0, 0, 0, 0);
    if (gy >= 0 && gy < HH && gx >= 0 && gx < WW) {
      const float* xb = x + b * 3 * HW + gy * WW + gx;
      v.x = f2bf(xb[0]); v.y = f2bf(xb[HW]); v.z = f2bf(xb[2 * HW]);
    }
    *(ushort4*)(xtb + e * 4) = v;
  }
  for (int e = tid; e < 176; e += 256) xtb[2704 + e] = 0;
  f32x4 acc[4][8];
#pragma unroll
  for (int a = 0; a < 4; ++a)
#pragma unroll
    for (int n = 0; n < 8; ++n) acc[a][n] = (f32x4){0.f, 0.f, 0.f, 0.f};
  __syncthreads();   // xtb ready; no further barriers until epilogue
  const int q8 = q * 8;
#pragma unroll
  for (int kc = 0; kc < 16; ++kc) {
    bf16x8 bf[8];
#pragma unroll
    for (int nt = 0; nt < 8; ++nt)
      bf[nt] = *(const bf16x8*)(Bp + ((kc * 128 + nt * 16 + m) * 32 + q8));
    const int s = kc * 32 + q8;
    const int u = (s * 745) >> 15;       // s/44, exact for s<512
    const int rem = s - 44 * u;
    const int a0 = s + 60 * u;           // ushort offset of tap (u,vv0,c=0)
    const int a1 = a0 + ((rem == 40) ? 64 : 4);
#pragma unroll
    for (int mt = 0; mt < 4; ++mt) {
      const int row = (wave << 2) + mt;
      const ushort* ab = xtb + (row * 26 + m) * 4;
      union { ushort us[8]; bf16x8 v; } af;
      *(ushort4*)(af.us)     = *(const ushort4*)(ab + a0);
      *(ushort4*)(af.us + 4) = *(const ushort4*)(ab + a1);
#pragma unroll
      for (int nt = 0; nt < 8; ++nt)
        acc[mt][nt] = MFMA16(af.v, bf[nt], acc[mt][nt]);
    }
  }
  // epilogue: bias + leaky + pool into per-q ps copy (conflict-free atomics)
  float bv[8];
#pragma unroll
  for (int nt = 0; nt < 8; ++nt) bv[nt] = p1b[nt * 16 + m];
  float* psq = ps + q * 1152;
#pragma unroll
  for (int mt = 0; mt < 4; ++mt) {
    int h = h0 + (wave << 2) + mt;
    if (h >= 250) continue;
    bool h0m = h < 84, h1m = (h >= 83 && h < 167), h2m = h >= 166;
#pragma unroll
    for (int r = 0; r < 4; ++r) {
      int w = w0 + (q << 2) + r;
      if (w >= 250) continue;
      bool w0m = w < 84, w1m = (w >= 83 && w < 167), w2m = w >= 166;
#pragma unroll
      for (int nt = 0; nt < 8; ++nt) {
        int o = (nt << 4) + m;
        float vz = acc[mt][nt][r] + bv[nt];
        vz = vz >= 0.f ? vz : 0.2f * vz;
        if (h0m) { if (w0m) atomicAdd(&psq[o], vz);        if (w1m) atomicAdd(&psq[128 + o], vz);
                   if (w2m) atomicAdd(&psq[256 + o], vz); }
        if (h1m) { if (w0m) atomicAdd(&psq[384 + o], vz);  if (w1m) atomicAdd(&psq[512 + o], vz);
                   if (w2m) atomicAdd(&psq[640 + o], vz); }
        if (h2m) { if (w0m) atomicAdd(&psq[768 + o], vz);  if (w1m) atomicAdd(&psq[896 + o], vz);
                   if (w2m) atomicAdd(&psq[1024 + o], vz); }
      }
    }
  }
  __syncthreads();
  // reduce 4 q-copies + coalesced per-tile partial store ([k*9+p] layout)
  const int tile = blockIdx.y * 16 + blockIdx.x;
  float* dst = pp + (size_t)(b * 256 + tile) * 1152;
  for (int e = tid; e < 1152; e += 256) {
    int idx = (e % 9) * 128 + (e / 9);
    dst[e] = ps[idx] + ps[1152 + idx] + ps[2304 + idx] + ps[3456 + idx];
  }
}

// ---------------------------------------------------------------------------
// Predictor tail: reduce the 256 per-tile partials, then fc chain + softmax.
// ---------------------------------------------------------------------------
__global__ __launch_bounds__(256) void k_pred2(const float* __restrict__ pp,
                                               const float* __restrict__ p2w,
                                               const float* __restrict__ p3w,
                                               float* __restrict__ kernw) {
  const int b = blockIdx.x;
  const int tid = threadIdx.x;
  __shared__ float hin[1152];
  __shared__ float h2p[1323];
  __shared__ float h3l[1323];
  __shared__ float mx[3], sm[3];
  for (int e = tid; e < 1152; e += 256) {
    float s = 0.f;
    const float* qp = pp + (size_t)b * 256 * 1152 + e;
#pragma unroll 4
    for (int t = 0; t < 256; ++t) s += qp[t * 1152];
    hin[e] = s * (1.f / 7056.f);
  }
  __syncthreads();
  for (int c = tid; c < 441; c += 256) {
    float z[9] = {0.f,0.f,0.f,0.f,0.f,0.f,0.f,0.f,0.f};
    const float* wr = p2w + c * 128;
    for (int k = 0; k < 128; k++) {
      float wv = wr[k];
      const float* hp = &hin[k * 9];
#pragma unroll
      for (int p = 0; p < 9; p++) z[p] += wv * hp[p];
    }
#pragma unroll
    for (int i = 0; i < 3; i++) {
      float s = 0.f;
#pragma unroll
      for (int jj = 0; jj < 3; jj++) {
        float zz = z[i * 3 + jj];
        s += (zz >= 0.f) ? zz : 0.2f * zz;
      }
      h2p[c * 3 + i] = s * (1.f / 3.f);
    }
  }
  __syncthreads();
  for (int c = tid; c < 441; c += 256) {
    float a0 = 0.f, a1 = 0.f, a2 = 0.f;
    const float* wr = p3w + c * 441;
    for (int k = 0; k < 441; k++) {
      float wv = wr[k];
      a0 += wv * h2p[k * 3];
      a1 += wv * h2p[k * 3 + 1];
      a2 += wv * h2p[k * 3 + 2];
    }
    h3l[c * 3] = a0; h3l[c * 3 + 1] = a1; h3l[c * 3 + 2] = a2;
  }
  __syncthreads();
  if (tid < 3) {
    float mxv = -1e30f;
    for (int c = 0; c < 441; c++) mxv = fmaxf(mxv, h3l[c * 3 + tid]);
    float s = 0.f;
    for (int c = 0; c < 441; c++) s += expf(h3l[c * 3 + tid] - mxv);
    mx[tid] = mxv; sm[tid] = 1.f / s;
  }
  __syncthreads();
  for (int f = tid; f < 1323; f += 256) {
    int i = f % 3;
    kernw[b * 1323 + f] = expf(h3l[f] - mx[i]) * sm[i];
  }
}

// ---------------------------------------------------------------------------
// Kernel D: per-sample dynamic conv (unchanged)
// ---------------------------------------------------------------------------
__global__ __launch_bounds__(256) void k_dyn(const float* __restrict__ x,
                                             const float* __restrict__ kernw,
                                             float* __restrict__ out1) {
  const int b = blockIdx.z;
  const int h0 = blockIdx.y * 16, w0 = blockIdx.x * 64;
  __shared__ float kl[1323];
  __shared__ float xt[3 * 36 * 84];
  for (int e = threadIdx.x; e < 1323; e += 256) kl[e] = kernw[b * 1323 + e];
  for (int e = threadIdx.x; e < 3 * 36 * 84; e += 256) {
    int ci = e / 3024, rem = e % 3024;
    int ty = rem / 84, tx = rem % 84;
    int gy = h0 + ty - 10, gx = w0 + tx - 10;
    xt[e] = (gy >= 0 && gy < HH && gx >= 0 && gx < WW)
                ? x[(b * 3 + ci) * HW + gy * WW + gx] : 0.f;
  }
  __syncthreads();
  const int wq = threadIdx.x & 15, r = threadIdx.x >> 4;
  float a0 = 0.f, a1 = 0.f, a2 = 0.f, a3 = 0.f;
  for (int ci = 0; ci < 3; ci++) {
    for (int kh = 0; kh < 21; kh++) {
      float rx[24];
      const float4* rp = (const float4*)&xt[ci * 3024 + (r + kh) * 84 + 4 * wq];
      float4* rv = (float4*)rx;
#pragma unroll
      for (int i = 0; i < 6; i++) rv[i] = rp[i];
      const float* wr = &kl[ci * 441 + kh * 21];
#pragma unroll
      for (int kw = 0; kw < 21; kw++) {
        float wv = wr[kw];
        a0 += wv * rx[kw];     a1 += wv * rx[kw + 1];
        a2 += wv * rx[kw + 2]; a3 += wv * rx[kw + 3];
      }
    }
  }
  int idx = b * HW + (h0 + r) * WW + w0 + 4 * wq;
  *(float4*)&out1[idx] = make_float4(a0, a1, a2, a3);
}

// ---------------------------------------------------------------------------
// Kernel E: ax_out (unchanged)
// ---------------------------------------------------------------------------
__global__ __launch_bounds__(256) void k_ax(const float* __restrict__ x,
                                            const float* __restrict__ csw,
                                            const float* __restrict__ csb,
                                            float* __restrict__ out2) {
  int idx = blockIdx.x * 256 + threadIdx.x;
  if (idx >= BB * 3 * HW) return;
  int w = idx & 255, h = (idx >> 8) & 255;
  int oc = (idx >> 16) % 3, b = idx / (3 * HW);
  float acc = csb[oc];
  for (int ic = 0; ic < 3; ic++) {
    const float* xc = x + (b * 3 + ic) * HW;
    const float* wp = csw + (oc * 3 + ic) * 9;
#pragma unroll
    for (int u = 0; u < 3; u++) {
      int iy = h + u - 1;
      if (iy < 0 || iy >= HH) continue;
#pragma unroll
      for (int v = 0; v < 3; v++) {
        int ix = w + v - 1;
        if (ix >= 0 && ix < WW) acc += xc[iy * WW + ix] * wp[u * 3 + v];
      }
    }
  }
  out2[idx] = acc;
}

// ---------------------------------------------------------------------------
// Fused conv as MFMA implicit GEMM (unchanged)
// ---------------------------------------------------------------------------
__global__ __launch_bounds__(256, 3) void k_fmma(const ushort* __restrict__ xgn,
                                                 const float* __restrict__ out1,
                                                 const ushort* __restrict__ Bw,
                                                 const ushort* __restrict__ BwZ,
                                                 const float* __restrict__ bias_tot,
                                                 float* __restrict__ outf) {
  __shared__ __align__(16) char smem[40080];
  ushort* xs  = (ushort*)smem;               // 18*18*32 bf16 = 20736
  float*  o1s = (float*)(smem + 20736);      // 20*20 f32     = 1600
  ushort* xs2 = (ushort*)(smem + 22336);     // 18*18*2 bf16  = 1296
  ushort* az  = (ushort*)(smem + 23632);     // 256*32 bf16   = 16384
  float*  st  = (float*)(smem + 23632);      // 16*257 f32    = 16448 (aliases az)
  const int b = blockIdx.z, h0 = blockIdx.y * 16, w0 = blockIdx.x * 16;
  const int tid = threadIdx.x, wave = tid >> 6, lane = tid & 63;
  const int m = lane & 15, q = lane >> 4;
  f32x4 acc[4][5];
#pragma unroll
  for (int a = 0; a < 4; ++a)
#pragma unroll
    for (int n = 0; n < 5; ++n) acc[a][n] = (f32x4){0.f, 0.f, 0.f, 0.f};

  for (int cc = 0; cc < 2; ++cc) {
    __syncthreads();
    for (int e = tid; e < 1296; e += 256) {
      int u = e & 3, p = e >> 2, py = p / 18, px = p % 18;
      int gy = h0 - 1 + py, gx = w0 - 1 + px;
      float4 v = make_float4(0.f, 0.f, 0.f, 0.f);
      if (gy >= 0 && gy < HH && gx >= 0 && gx < WW)
        v = *(const float4*)(xgn + (size_t)(b * HW + gy * WW + gx) * 72 + cc * 32 + u * 8);
      *(float4*)(xs + p * 32 + u * 8) = v;
    }
    __syncthreads();
#pragma unroll
    for (int t = 0; t < 9; ++t) {
      const int u = t / 3, v = t % 3;
      bf16x8 bf[5];
#pragma unroll
      for (int nt = 0; nt < 5; ++nt)
        bf[nt] = *(const bf16x8*)(Bw + (((cc * 9 + t) * 80 + nt * 16 + m) * 32 + q * 8));
#pragma unroll
      for (int mt = 0; mt < 4; ++mt) {
        int row = (wave << 2) + mt;
        bf16x8 af = *(const bf16x8*)(xs + ((row + u) * 18 + m + v) * 32 + q * 8);
#pragma unroll
        for (int nt = 0; nt < 5; ++nt)
          acc[mt][nt] = MFMA16(af, bf[nt], acc[mt][nt]);
      }
    }
  }
  __syncthreads();
  for (int e = tid; e < 324; e += 256) {
    int py = e / 18, px = e % 18, gy = h0 - 1 + py, gx = w0 - 1 + px;
    uint32_t v = 0;
    if (gy >= 0 && gy < HH && gx >= 0 && gx < WW)
      v = *(const uint32_t*)(xgn + (size_t)(b * HW + gy * WW + gx) * 72 + 64);
    *(uint32_t*)(xs2 + e * 2) = v;
  }
  for (int e = tid; e < 400; e += 256) {
    int py = e / 20, px = e % 20, gy = h0 - 2 + py, gx = w0 - 2 + px;
    o1s[e] = (gy >= 0 && gy < HH && gx >= 0 && gx < WW) ? out1[b * HW + gy * WW + gx] : 0.f;
  }
  __syncthreads();
  const int bpy = tid >> 4, bpx = tid & 15;
#pragma unroll
  for (int zc = 0; zc < 2; ++zc) {
    union { ushort us[32]; float4 f4[4]; } vals;
    if (zc == 0) {
#pragma unroll
      for (int s = 0; s < 18; ++s) {
        int ch = s / 9, a = s % 9, u = a / 3, v = a % 3;
        vals.us[s] = xs2[((bpy + u) * 18 + bpx + v) * 2 + ch];
      }
#pragma unroll
      for (int d = 0; d < 14; ++d)
        vals.us[18 + d] = f2bf(o1s[(bpy + d / 5) * 20 + bpx + d % 5]);
    } else {
#pragma unroll
      for (int s = 0; s < 11; ++s) {
        int d = 14 + s;
        vals.us[s] = f2bf(o1s[(bpy + d / 5) * 20 + bpx + d % 5]);
      }
#pragma unroll
      for (int s = 11; s < 32; ++s) vals.us[s] = 0;
    }
    __syncthreads();
#pragma unroll
    for (int u = 0; u < 4; ++u)
      *(float4*)(az + tid * 32 + ((u ^ (tid & 3)) << 3)) = vals.f4[u];
    __syncthreads();
    bf16x8 bf[5];
#pragma unroll
    for (int nt = 0; nt < 5; ++nt)
      bf[nt] = *(const bf16x8*)(BwZ + ((zc * 80 + nt * 16 + m) * 32 + q * 8));
#pragma unroll
    for (int mt = 0; mt < 4; ++mt) {
      int px = (((wave << 2) + mt) << 4) + m;
      bf16x8 af = *(const bf16x8*)(az + px * 32 + ((q ^ (px & 3)) << 3));
#pragma unroll
      for (int nt = 0; nt < 5; ++nt)
        acc[mt][nt] = MFMA16(af, bf[nt], acc[mt][nt]);
    }
  }
#pragma unroll 1
  for (int nt = 0; nt < 5; ++nt) {
    __syncthreads();
#pragma unroll
    for (int mt = 0; mt < 4; ++mt) {
      int pxb = (((wave << 2) + mt) << 4);
#pragma unroll
      for (int r = 0; r < 4; ++r)
        st[m * 257 + pxb + q * 4 + r] = acc[mt][nt][r];
    }
    __syncthreads();
#pragma unroll
    for (int kk = 0; kk < 16; ++kk) {
      int o = nt * 16 + kk;
      if (o < 66) {
        float bvv = bias_tot[o];
        outf[((b * 66 + o) * HH + h0 + (tid >> 4)) * WW + w0 + (tid & 15)] =
            st[kk * 257 + tid] + bvv;
      }
    }
  }
}

// ---------------------------------------------------------------------------
// Border fixup (unchanged)
// ---------------------------------------------------------------------------
__global__ __launch_bounds__(256) void k_fix(const float* __restrict__ out1,
                                             const float* __restrict__ T,
                                             const float* __restrict__ TB,
                                             float* __restrict__ outf) {
  int idx = blockIdx.x * 256 + threadIdx.x;
  if (idx >= 8 * 1020 * 66) return;
  int b = idx / (1020 * 66);
  int rem = idx % (1020 * 66);
  int pi = rem / 66, o = rem % 66;
  int ph, pw;
  if (pi < 256)      { ph = 0;        pw = pi; }
  else if (pi < 512) { ph = 255;      pw = pi - 256; }
  else if (pi < 766) { ph = pi - 511; pw = 0; }
  else               { ph = pi - 765; pw = 255; }
  float corr = 0.f;
#pragma unroll
  for (int a = 0; a < 9; ++a) {
    int ua = a / 3, va = a % 3;
    int qh = ph + ua - 1, qw = pw + va - 1;
    if (qh >= 0 && qh < HH && qw >= 0 && qw < WW) continue;
    float s = TB[o * 9 + a];
#pragma unroll
    for (int t2 = 0; t2 < 9; ++t2) {
      int rh = qh + t2 / 3 - 1, rw = qw + t2 % 3 - 1;
      if (rh >= 0 && rh < HH && rw >= 0 && rw < WW)
        s += out1[b * HW + rh * WW + rw] * T[(o * 9 + a) * 9 + t2];
    }
    corr += s;
  }
  outf[((b * 66 + o) * HH + ph) * WW + pw] -= corr;
}

// ---------------------------------------------------------------------------
extern "C" void kernel_launch(void* const* d_in, const int* in_sizes, int n_in,
                              void* d_out, int out_size, void* d_ws, size_t ws_size,
                              hipStream_t stream) {
  const float* x   = (const float*)d_in[0];
  const float* wg  = (const float*)d_in[1];
  const float* p1w = (const float*)d_in[2];
  const float* p1b = (const float*)d_in[3];
  const float* p2w = (const float*)d_in[4];
  const float* p3w = (const float*)d_in[5];
  const float* csw = (const float*)d_in[6];
  const float* csb = (const float*)d_in[7];
  const float* trw = (const float*)d_in[8];
  const float* trb = (const float*)d_in[9];
  const float* fuw = (const float*)d_in[10];
  const float* fub = (const float*)d_in[11];
  float* outf = (float*)d_out;                 // fused: 8*66*256*256
  float* out2 = outf + 34603008;               // ax_out: 8*3*256*256
  char* ws = (char*)d_ws;
  __hip_bfloat16* xg = (__hip_bfloat16*)(ws + OFF_XG);
  float* pp      = (float*)(ws + OFF_PP);
  ushort* Bp     = (ushort*)(ws + OFF_BP);
  ushort* xgn    = (ushort*)(ws + OFF_XGN);
  float* out1    = (float*)(ws + OFF_OUT1);
  float* kernw   = (float*)(ws + OFF_KERN);
  ushort* Bw     = (ushort*)(ws + OFF_BW);
  ushort* BwZ    = (ushort*)(ws + OFF_BWZ);
  float* biasT   = (float*)(ws + OFF_BIAS);
  float* TBp     = (float*)(ws + OFF_TB);
  float* Tp      = (float*)(ws + OFF_T);

  hipLaunchKernelGGL(k_prepA, dim3(460), dim3(256), 0, stream,
                     fuw, trw, trb, p1w, Tp, TBp, Bw, Bp);
  hipLaunchKernelGGL(k_prepB, dim3(21), dim3(256), 0, stream,
                     fuw, fub, Tp, TBp, BwZ, biasT);
  hipLaunchKernelGGL(k_xgauss, dim3(1, 32, 8 * 24), dim3(256), 0, stream, x, wg, xg);
  hipLaunchKernelGGL(k_tr, dim3(8192), dim3(256), 0, stream, (const ushort*)xg, xgn);
  hipLaunchKernelGGL(k_pmm, dim3(16, 16, 8), dim3(256), 0, stream, x, Bp, p1b, pp);
  hipLaunchKernelGGL(k_pred2, dim3(8), dim3(256), 0, stream, pp, p2w, p3w, kernw);
  hipLaunchKernelGGL(k_dyn, dim3(4, 16, 8), dim3(256), 0, stream, x, kernw, out1);
  hipLaunchKernelGGL(k_fmma, dim3(16, 16, 8), dim3(256), 0, stream,
                     xgn, out1, Bw, BwZ, biasT, outf);
  hipLaunchKernelGGL(k_fix, dim3(2104), dim3(256), 0, stream, out1, Tp, TBp, outf);
  hipLaunchKernelGGL(k_ax, dim3(6144), dim3(256), 0, stream, x, csw, csb, out2);
}

// Round 10
// 1324.970 us; speedup vs baseline: 1.1316x; 1.0149x over previous
//
#include <hip/hip_runtime.h>
#include <hip/hip_bf16.h>

#define BB 8
#define HH 256
#define WW 256
#define HW 65536

typedef __attribute__((ext_vector_type(8))) short bf16x8;
typedef __attribute__((ext_vector_type(4))) float f32x4;
typedef __attribute__((ext_vector_type(16))) float f32x16;
typedef __attribute__((ext_vector_type(8))) unsigned short u16x8;
#define MFMA16(a, b, c) __builtin_amdgcn_mfma_f32_16x16x32_bf16(a, b, c, 0, 0, 0)
#define MFMA32(a, b, c) __builtin_amdgcn_mfma_f32_32x32x16_bf16(a, b, c, 0, 0, 0)

__device__ __forceinline__ ushort f2bf(float f) {
  union { float f; uint32_t u; } c; c.f = f;
  uint32_t r = (c.u + 0x7fffu + ((c.u >> 16) & 1u)) >> 16;
  return (ushort)r;
}

// ---------------- workspace layout (bytes) ----------------
#define OFF_XG    0            // xg unique-maps bf16: 8*24*65536*2 = 25,165,824
#define OFF_PP    25165824     // pooled partials f32: 2048*1152*4  = 9,437,184 (ends 34,603,008)
#define OFF_BP    34603008     // Bp bf16 (32x32 B-frag layout): 32*4*32*16 u16 = 131,072
#define OFF_XGN   69206016     // xg NHWC bf16 (72ch padded):   = 75,497,472
#define OFF_OUT1  144703488    // out1 f32: 8*65536*4           = 2,097,152
#define OFF_KERN  146837504    // kern f32: 8*1323*4            = 42,336 (+pad)
#define OFF_BW    146880000    // Bw bf16: [cc(2)][t9][o80][32]; alloc 138,240
#define OFF_BWZ   147018240    // BwZ bf16: 2*80*32*2           = 10,240
#define OFF_BIAS  147126784    // bias_tot f32: 80*4 (+pad)
#define OFF_TB    147127296    // TB f32: 66*9*4 (+pad)
#define OFF_T     147129856    // T f32: 66*81*4 (+pad)

// ---------------------------------------------------------------------------
// prepA: T, TB, Bw, and Bp in the 32x32x16 B-fragment layout:
//   Bp[kk(32)][nt(4)][col(32)][half(2)][8]; k = kk*16 + half*8 + j (K'=512),
//   K' = u*44 + vv*4 + c (c==3 and k'>=484 are zero pad); ch = nt*32 + col.
// ---------------------------------------------------------------------------
__global__ __launch_bounds__(256) void k_prepA(const float* __restrict__ fuw,
                                               const float* __restrict__ trw,
                                               const float* __restrict__ trb,
                                               const float* __restrict__ p1w,
                                               float* __restrict__ T,
                                               float* __restrict__ TB,
                                               ushort* __restrict__ Bw,
                                               ushort* __restrict__ Bp) {
  int i = blockIdx.x * 256 + threadIdx.x;
  if (i < 5346) {  // T
    int o = i / 81, a = (i / 9) % 9, s = i % 9;
    float acc = 0.f;
    for (int cp = 0; cp < 66; ++cp)
      acc += fuw[(o * 132 + 66 + cp) * 9 + a] *
             (trw[(cp * 3) * 9 + s] + trw[(cp * 3 + 1) * 9 + s] + trw[(cp * 3 + 2) * 9 + s]);
    T[i] = acc; return;
  }
  i -= 5346;
  if (i < 594) {  // TB
    int o = i / 9, a = i % 9;
    float acc = 0.f;
    for (int cp = 0; cp < 66; ++cp) acc += trb[cp] * fuw[(o * 132 + 66 + cp) * 9 + a];
    TB[i] = acc; return;
  }
  i -= 594;
  if (i < 2 * 9 * 80 * 32) {  // Bw
    int cc = i / 23040, t = (i / 2560) % 9, o = (i / 32) % 80, kl = i & 31;
    int c = cc * 32 + kl;
    Bw[i] = (o < 66) ? f2bf(fuw[(o * 132 + c) * 9 + t]) : 0;
    return;
  }
  i -= 2 * 9 * 80 * 32;
  if (i < 65536) {  // Bp (32x32 fragment layout)
    int kk = i / 2048, r = i % 2048;
    int nt = r / 512, r2 = r % 512;
    int col = r2 / 16, r3 = r2 % 16;
    int half = r3 / 8, j = r3 % 8;
    int k = kk * 16 + half * 8 + j;
    int ch = nt * 32 + col;
    float v = 0.f;
    if (k < 484) { int u = k / 44, r4 = k % 44, vv = r4 / 4, c = r4 & 3;
                   if (c < 3) v = p1w[(ch * 3 + c) * 121 + u * 11 + vv]; }
    Bp[i] = f2bf(v);
    return;
  }
}

__device__ __forceinline__ float W5val(int o, int d, const float* T) {
  int dy = d / 5, dx = d % 5;
  float acc = 0.f;
  for (int ua = 0; ua < 3; ++ua) {
    int us = dy - ua; if (us < 0 || us > 2) continue;
    for (int va = 0; va < 3; ++va) {
      int vs = dx - va; if (vs < 0 || vs > 2) continue;
      acc += T[(o * 9 + ua * 3 + va) * 9 + us * 3 + vs];
    }
  }
  return acc;
}

// prepB: BwZ (z-chunk weights: xg ch64/65 taps + composed 5x5 W5) and bias_tot
__global__ __launch_bounds__(256) void k_prepB(const float* __restrict__ fuw,
                                               const float* __restrict__ fub,
                                               const float* __restrict__ T,
                                               const float* __restrict__ TB,
                                               ushort* __restrict__ BwZ,
                                               float* __restrict__ bias_tot) {
  int i = blockIdx.x * 256 + threadIdx.x;
  if (i < 5120) {
    int zc = i / 2560, o = (i / 32) % 80, s = i & 31;
    float v = 0.f;
    if (o < 66) {
      if (zc == 0) {
        if (s < 18) { int ch = 64 + s / 9, a = s % 9; v = fuw[(o * 132 + ch) * 9 + a]; }
        else        { v = W5val(o, s - 18, T); }
      } else {
        if (s < 11) v = W5val(o, 14 + s, T);
      }
    }
    BwZ[i] = f2bf(v); return;
  }
  i -= 5120;
  if (i < 80) {
    float v = 0.f;
    if (i < 66) { v = fub[i]; for (int a = 0; a < 9; ++a) v += TB[i * 9 + a]; }
    bias_tot[i] = v;
  }
}

// ---------------------------------------------------------------------------
// Kernel A: x_gauss — 24 unique (g, j) maps; k_tr fans out to 66 channels.
// ---------------------------------------------------------------------------
template <int KS>
__device__ __forceinline__ void xg_conv(const float* __restrict__ xt,
                                        const float* __restrict__ wgp,
                                        float* a, int r, int wq) {
  constexpr int P0 = (21 - KS) / 2;
  constexpr int Q0 = P0 & ~3;
  constexpr int D0 = P0 - Q0;
  constexpr int NL = ((P0 + KS + 6) >> 2) - (P0 >> 2) + 1;
#pragma unroll 1
  for (int kh = P0; kh < P0 + KS; ++kh) {
    float rx[NL * 4];
    const int F0 = (r + kh) * 320 + 8 * wq + Q0;
#pragma unroll
    for (int i = 0; i < NL; ++i) {
      int Fi = F0 + 4 * i;
      *(float4*)(rx + 4 * i) = *(const float4*)(xt + (Fi ^ (((Fi >> 5) & 1) << 2)));
    }
    const float* wr = wgp + kh * 21 + P0;  // wave-uniform -> scalar loads
#pragma unroll
    for (int t = 0; t < KS; ++t) {
      float wv = wr[t];
#pragma unroll
      for (int u = 0; u < 8; ++u) a[u] += wv * rx[D0 + t + u];
    }
  }
}

__global__ __launch_bounds__(256, 4) void k_xgauss(const float* __restrict__ x,
                                                   const float* __restrict__ wg,
                                                   __hip_bfloat16* __restrict__ xg) {
  const int bu = blockIdx.z;
  const int b = bu / 24, u = bu % 24;
  const int g = u >> 3;              // input channel
  const int j = (u & 7) + 7 * g;     // kernel index (o/3)
  const int h0 = blockIdx.y * 8;
  __shared__ __align__(16) float xt[28 * 320];
  const float* xp = x + (b * 3 + g) * HW;
  for (int e = threadIdx.x; e < 28 * 320; e += 256) {
    int row = e / 320, col = e % 320;
    int gy = h0 + row - 10, gx = col - 10;
    float v = (gy >= 0 && gy < HH && gx >= 0 && gx < WW) ? xp[gy * WW + gx] : 0.f;
    xt[e ^ (((e >> 5) & 1) << 2)] = v;
  }
  __syncthreads();
  int i_ = j - 1;
  int im = (i_ - 1 > 0) ? (i_ - 1) : 0;
  const int ks = (j == 0) ? 1 : 3 + 2 * (im >> 1);
  const int wq = threadIdx.x & 31, r = threadIdx.x >> 5;
  const float* wgp = wg + (3 * j) * 441;
  float a[8] = {0.f, 0.f, 0.f, 0.f, 0.f, 0.f, 0.f, 0.f};
  switch (ks) {
    case 1:  xg_conv<1>(xt, wgp, a, r, wq); break;
    case 3:  xg_conv<3>(xt, wgp, a, r, wq); break;
    case 5:  xg_conv<5>(xt, wgp, a, r, wq); break;
    case 7:  xg_conv<7>(xt, wgp, a, r, wq); break;
    case 9:  xg_conv<9>(xt, wgp, a, r, wq); break;
    case 11: xg_conv<11>(xt, wgp, a, r, wq); break;
    case 13: xg_conv<13>(xt, wgp, a, r, wq); break;
    case 15: xg_conv<15>(xt, wgp, a, r, wq); break;
    case 17: xg_conv<17>(xt, wgp, a, r, wq); break;
    case 19: xg_conv<19>(xt, wgp, a, r, wq); break;
    default: xg_conv<21>(xt, wgp, a, r, wq); break;
  }
  u16x8 ov;
#pragma unroll
  for (int k = 0; k < 8; ++k) ov[k] = f2bf(a[k]);
  int oidx = (bu * HW) + (h0 + r) * WW + 8 * wq;
  *(u16x8*)((ushort*)xg + oidx) = ov;
}

// ---------------------------------------------------------------------------
// Transpose xg unique-maps -> NHWC (72-ch padded), fanning 24 maps out to 66
// channels: channel c reads unique map uid = c/3 + c/22.
// ---------------------------------------------------------------------------
__global__ __launch_bounds__(256) void k_tr(const ushort* __restrict__ xg,
                                            ushort* __restrict__ xgn) {
  __shared__ ushort ls[64 * 72];
  int p0 = blockIdx.x * 64;
  int b = p0 >> 16, sp = p0 & 65535;
  for (int e = threadIdx.x; e < 72 * 64; e += 256) {
    int c = e >> 6, i = e & 63;
    int uc = c / 3 + c / 22;
    ls[i * 72 + c] = (c < 66) ? xg[(size_t)(b * 24 + uc) * HW + sp + i] : (ushort)0;
  }
  __syncthreads();
  for (int e = threadIdx.x; e < 576; e += 256) {
    *(float4*)(xgn + (size_t)p0 * 72 + e * 8) = *(const float4*)(ls + e * 8);
  }
}

// ---------------------------------------------------------------------------
// Predictor stage 1 — 32x32x16 MFMA (half the MFMA instructions of r9).
// r7-r9 invariant: all pipes <10%, wave-throughput/CU constant across 2-26
// concurrent waves => per-MFMA-instruction cost dominates (~58 cy apparent).
// 32x32 tiles: per wave 2 px-tiles x 4 ch-tiles, 32 k-steps x 8 MFMA = 256
// MFMA/wave (was 512), same FLOP, faster pipe (2382 vs 2075 TF ubench).
//  * A: row=lane&31 (pixel), k=(lane>>5)*8+j — same gather math as r9.
//  * C/D: col=lane&31 (ch), row=(reg&3)+8*(reg>>2)+4*(lane>>5) [guide m74].
//  * ps split 2-way by half (only same-address wave collision).
//  * xtb padded to 4096 + zeroed (closes r9's benign OOB-read window).
// ---------------------------------------------------------------------------
__global__ __launch_bounds__(256, 2) void k_pmm(const float* __restrict__ x,
                                                const ushort* __restrict__ Bp,
                                                const float* __restrict__ p1b,
                                                float* __restrict__ pp) {
  __shared__ __align__(16) ushort xtb[4096];   // 2704 data + zero pad
  __shared__ float ps[2 * 1152];
  const int b = blockIdx.z, h0 = blockIdx.y * 16, w0 = blockIdx.x * 16;
  const int tid = threadIdx.x, wave = tid >> 6, lane = tid & 63;
  const int col = lane & 31, half = lane >> 5;
  for (int e = tid; e < 2304; e += 256) ps[e] = 0.f;
  for (int e = tid; e < 676; e += 256) {
    int py = e / 26, pxc = e % 26, gy = h0 - 2 + py, gx = w0 - 2 + pxc;
    ushort4 v = make_ushort4(0, 0, 0, 0);
    if (gy >= 0 && gy < HH && gx >= 0 && gx < WW) {
      const float* xb = x + b * 3 * HW + gy * WW + gx;
      v.x = f2bf(xb[0]); v.y = f2bf(xb[HW]); v.z = f2bf(xb[2 * HW]);
    }
    *(ushort4*)(xtb + e * 4) = v;
  }
  for (int e = tid; e < 1392; e += 256) xtb[2704 + e] = 0;
  f32x16 acc[2][4];
#pragma unroll
  for (int p = 0; p < 2; ++p)
#pragma unroll
    for (int n = 0; n < 4; ++n) acc[p][n] = (f32x16)(0.f);
  __syncthreads();   // xtb ready; no further barriers until epilogue
  // per-lane pixel base for pt=0: px = wave*64 + row32 (row32 = col here = lane&31)
  const int px0 = (wave << 6) + col;
  const int ab0 = ((px0 >> 4) * 26 + (px0 & 15)) * 4;   // ushort offset
  const int ab1 = (((px0 + 32) >> 4) * 26 + (px0 & 15)) * 4;
#pragma unroll
  for (int kk = 0; kk < 32; ++kk) {
    bf16x8 bf[4];
#pragma unroll
    for (int nt = 0; nt < 4; ++nt)
      bf[nt] = *(const bf16x8*)(Bp + (kk * 2048 + nt * 512 + col * 16 + half * 8));
    const int s = kk * 16 + half * 8;
    const int u = (s * 745) >> 15;       // s/44, exact for s<512
    const int rem = s - 44 * u;
    const int a0 = s + 60 * u;
    const int a1 = a0 + ((rem == 40) ? 64 : 4);
#pragma unroll
    for (int pt = 0; pt < 2; ++pt) {
      const ushort* ab = xtb + (pt ? ab1 : ab0);
      union { ushort us[8]; bf16x8 v; } af;
      *(ushort4*)(af.us)     = *(const ushort4*)(ab + a0);
      *(ushort4*)(af.us + 4) = *(const ushort4*)(ab + a1);
#pragma unroll
      for (int nt = 0; nt < 4; ++nt)
        acc[pt][nt] = MFMA32(af.v, bf[nt], acc[pt][nt]);
    }
  }
  // epilogue: bias + leaky + pool into per-half ps copy
  float bv[4];
#pragma unroll
  for (int nt = 0; nt < 4; ++nt) bv[nt] = p1b[nt * 32 + col];
  float* psq = ps + half * 1152;
#pragma unroll
  for (int pt = 0; pt < 2; ++pt) {
#pragma unroll
    for (int r = 0; r < 16; ++r) {
      int row = (r & 3) + 8 * (r >> 2) + 4 * half;
      int px = (wave << 6) + (pt << 5) + row;
      int h = h0 + (px >> 4), w = w0 + (px & 15);
      if (h >= 250 || w >= 250) continue;
      bool h0m = h < 84, h1m = (h >= 83 && h < 167), h2m = h >= 166;
      bool w0m = w < 84, w1m = (w >= 83 && w < 167), w2m = w >= 166;
#pragma unroll
      for (int nt = 0; nt < 4; ++nt) {
        int o = nt * 32 + col;
        float vz = acc[pt][nt][r] + bv[nt];
        vz = vz >= 0.f ? vz : 0.2f * vz;
        if (h0m) { if (w0m) atomicAdd(&psq[o], vz);        if (w1m) atomicAdd(&psq[128 + o], vz);
                   if (w2m) atomicAdd(&psq[256 + o], vz); }
        if (h1m) { if (w0m) atomicAdd(&psq[384 + o], vz);  if (w1m) atomicAdd(&psq[512 + o], vz);
                   if (w2m) atomicAdd(&psq[640 + o], vz); }
        if (h2m) { if (w0m) atomicAdd(&psq[768 + o], vz);  if (w1m) atomicAdd(&psq[896 + o], vz);
                   if (w2m) atomicAdd(&psq[1024 + o], vz); }
      }
    }
  }
  __syncthreads();
  // reduce 2 half-copies + coalesced per-tile partial store ([k*9+p] layout)
  const int tile = blockIdx.y * 16 + blockIdx.x;
  float* dst = pp + (size_t)(b * 256 + tile) * 1152;
  for (int e = tid; e < 1152; e += 256) {
    int idx = (e % 9) * 128 + (e / 9);
    dst[e] = ps[idx] + ps[1152 + idx];
  }
}

// ---------------------------------------------------------------------------
// Predictor tail: reduce the 256 per-tile partials, then fc chain + softmax.
// ---------------------------------------------------------------------------
__global__ __launch_bounds__(256) void k_pred2(const float* __restrict__ pp,
                                               const float* __restrict__ p2w,
                                               const float* __restrict__ p3w,
                                               float* __restrict__ kernw) {
  const int b = blockIdx.x;
  const int tid = threadIdx.x;
  __shared__ float hin[1152];
  __shared__ float h2p[1323];
  __shared__ float h3l[1323];
  __shared__ float mx[3], sm[3];
  for (int e = tid; e < 1152; e += 256) {
    float s = 0.f;
    const float* qp = pp + (size_t)b * 256 * 1152 + e;
#pragma unroll 4
    for (int t = 0; t < 256; ++t) s += qp[t * 1152];
    hin[e] = s * (1.f / 7056.f);
  }
  __syncthreads();
  for (int c = tid; c < 441; c += 256) {
    float z[9] = {0.f,0.f,0.f,0.f,0.f,0.f,0.f,0.f,0.f};
    const float* wr = p2w + c * 128;
    for (int k = 0; k < 128; k++) {
      float wv = wr[k];
      const float* hp = &hin[k * 9];
#pragma unroll
      for (int p = 0; p < 9; p++) z[p] += wv * hp[p];
    }
#pragma unroll
    for (int i = 0; i < 3; i++) {
      float s = 0.f;
#pragma unroll
      for (int jj = 0; jj < 3; jj++) {
        float zz = z[i * 3 + jj];
        s += (zz >= 0.f) ? zz : 0.2f * zz;
      }
      h2p[c * 3 + i] = s * (1.f / 3.f);
    }
  }
  __syncthreads();
  for (int c = tid; c < 441; c += 256) {
    float a0 = 0.f, a1 = 0.f, a2 = 0.f;
    const float* wr = p3w + c * 441;
    for (int k = 0; k < 441; k++) {
      float wv = wr[k];
      a0 += wv * h2p[k * 3];
      a1 += wv * h2p[k * 3 + 1];
      a2 += wv * h2p[k * 3 + 2];
    }
    h3l[c * 3] = a0; h3l[c * 3 + 1] = a1; h3l[c * 3 + 2] = a2;
  }
  __syncthreads();
  if (tid < 3) {
    float mxv = -1e30f;
    for (int c = 0; c < 441; c++) mxv = fmaxf(mxv, h3l[c * 3 + tid]);
    float s = 0.f;
    for (int c = 0; c < 441; c++) s += expf(h3l[c * 3 + tid] - mxv);
    mx[tid] = mxv; sm[tid] = 1.f / s;
  }
  __syncthreads();
  for (int f = tid; f < 1323; f += 256) {
    int i = f % 3;
    kernw[b * 1323 + f] = expf(h3l[f] - mx[i]) * sm[i];
  }
}

// ---------------------------------------------------------------------------
// Kernel D: per-sample dynamic conv (unchanged)
// ---------------------------------------------------------------------------
__global__ __launch_bounds__(256) void k_dyn(const float* __restrict__ x,
                                             const float* __restrict__ kernw,
                                             float* __restrict__ out1) {
  const int b = blockIdx.z;
  const int h0 = blockIdx.y * 16, w0 = blockIdx.x * 64;
  __shared__ float kl[1323];
  __shared__ float xt[3 * 36 * 84];
  for (int e = threadIdx.x; e < 1323; e += 256) kl[e] = kernw[b * 1323 + e];
  for (int e = threadIdx.x; e < 3 * 36 * 84; e += 256) {
    int ci = e / 3024, rem = e % 3024;
    int ty = rem / 84, tx = rem % 84;
    int gy = h0 + ty - 10, gx = w0 + tx - 10;
    xt[e] = (gy >= 0 && gy < HH && gx >= 0 && gx < WW)
                ? x[(b * 3 + ci) * HW + gy * WW + gx] : 0.f;
  }
  __syncthreads();
  const int wq = threadIdx.x & 15, r = threadIdx.x >> 4;
  float a0 = 0.f, a1 = 0.f, a2 = 0.f, a3 = 0.f;
  for (int ci = 0; ci < 3; ci++) {
    for (int kh = 0; kh < 21; kh++) {
      float rx[24];
      const float4* rp = (const float4*)&xt[ci * 3024 + (r + kh) * 84 + 4 * wq];
      float4* rv = (float4*)rx;
#pragma unroll
      for (int i = 0; i < 6; i++) rv[i] = rp[i];
      const float* wr = &kl[ci * 441 + kh * 21];
#pragma unroll
      for (int kw = 0; kw < 21; kw++) {
        float wv = wr[kw];
        a0 += wv * rx[kw];     a1 += wv * rx[kw + 1];
        a2 += wv * rx[kw + 2]; a3 += wv * rx[kw + 3];
      }
    }
  }
  int idx = b * HW + (h0 + r) * WW + w0 + 4 * wq;
  *(float4*)&out1[idx] = make_float4(a0, a1, a2, a3);
}

// ---------------------------------------------------------------------------
// Kernel E: ax_out (unchanged)
// ---------------------------------------------------------------------------
__global__ __launch_bounds__(256) void k_ax(const float* __restrict__ x,
                                            const float* __restrict__ csw,
                                            const float* __restrict__ csb,
                                            float* __restrict__ out2) {
  int idx = blockIdx.x * 256 + threadIdx.x;
  if (idx >= BB * 3 * HW) return;
  int w = idx & 255, h = (idx >> 8) & 255;
  int oc = (idx >> 16) % 3, b = idx / (3 * HW);
  float acc = csb[oc];
  for (int ic = 0; ic < 3; ic++) {
    const float* xc = x + (b * 3 + ic) * HW;
    const float* wp = csw + (oc * 3 + ic) * 9;
#pragma unroll
    for (int u = 0; u < 3; u++) {
      int iy = h + u - 1;
      if (iy < 0 || iy >= HH) continue;
#pragma unroll
      for (int v = 0; v < 3; v++) {
        int ix = w + v - 1;
        if (ix >= 0 && ix < WW) acc += xc[iy * WW + ix] * wp[u * 3 + v];
      }
    }
  }
  out2[idx] = acc;
}

// ---------------------------------------------------------------------------
// Fused conv as MFMA implicit GEMM (unchanged)
// ---------------------------------------------------------------------------
__global__ __launch_bounds__(256, 3) void k_fmma(const ushort* __restrict__ xgn,
                                                 const float* __restrict__ out1,
                                                 const ushort* __restrict__ Bw,
                                                 const ushort* __restrict__ BwZ,
                                                 const float* __restrict__ bias_tot,
                                                 float* __restrict__ outf) {
  __shared__ __align__(16) char smem[40080];
  ushort* xs  = (ushort*)smem;               // 18*18*32 bf16 = 20736
  float*  o1s = (float*)(smem + 20736);      // 20*20 f32     = 1600
  ushort* xs2 = (ushort*)(smem + 22336);     // 18*18*2 bf16  = 1296
  ushort* az  = (ushort*)(smem + 23632);     // 256*32 bf16   = 16384
  float*  st  = (float*)(smem + 23632);      // 16*257 f32    = 16448 (aliases az)
  const int b = blockIdx.z, h0 = blockIdx.y * 16, w0 = blockIdx.x * 16;
  const int tid = threadIdx.x, wave = tid >> 6, lane = tid & 63;
  const int m = lane & 15, q = lane >> 4;
  f32x4 acc[4][5];
#pragma unroll
  for (int a = 0; a < 4; ++a)
#pragma unroll
    for (int n = 0; n < 5; ++n) acc[a][n] = (f32x4){0.f, 0.f, 0.f, 0.f};

  for (int cc = 0; cc < 2; ++cc) {
    __syncthreads();
    for (int e = tid; e < 1296; e += 256) {
      int u = e & 3, p = e >> 2, py = p / 18, px = p % 18;
      int gy = h0 - 1 + py, gx = w0 - 1 + px;
      float4 v = make_float4(0.f, 0.f, 0.f, 0.f);
      if (gy >= 0 && gy < HH && gx >= 0 && gx < WW)
        v = *(const float4*)(xgn + (size_t)(b * HW + gy * WW + gx) * 72 + cc * 32 + u * 8);
      *(float4*)(xs + p * 32 + u * 8) = v;
    }
    __syncthreads();
#pragma unroll
    for (int t = 0; t < 9; ++t) {
      const int u = t / 3, v = t % 3;
      bf16x8 bf[5];
#pragma unroll
      for (int nt = 0; nt < 5; ++nt)
        bf[nt] = *(const bf16x8*)(Bw + (((cc * 9 + t) * 80 + nt * 16 + m) * 32 + q * 8));
#pragma unroll
      for (int mt = 0; mt < 4; ++mt) {
        int row = (wave << 2) + mt;
        bf16x8 af = *(const bf16x8*)(xs + ((row + u) * 18 + m + v) * 32 + q * 8);
#pragma unroll
        for (int nt = 0; nt < 5; ++nt)
          acc[mt][nt] = MFMA16(af, bf[nt], acc[mt][nt]);
      }
    }
  }
  __syncthreads();
  for (int e = tid; e < 324; e += 256) {
    int py = e / 18, px = e % 18, gy = h0 - 1 + py, gx = w0 - 1 + px;
    uint32_t v = 0;
    if (gy >= 0 && gy < HH && gx >= 0 && gx < WW)
      v = *(const uint32_t*)(xgn + (size_t)(b * HW + gy * WW + gx) * 72 + 64);
    *(uint32_t*)(xs2 + e * 2) = v;
  }
  for (int e = tid; e < 400; e += 256) {
    int py = e / 20, px = e % 20, gy = h0 - 2 + py, gx = w0 - 2 + px;
    o1s[e] = (gy >= 0 && gy < HH && gx >= 0 && gx < WW) ? out1[b * HW + gy * WW + gx] : 0.f;
  }
  __syncthreads();
  const int bpy = tid >> 4, bpx = tid & 15;
#pragma unroll
  for (int zc = 0; zc < 2; ++zc) {
    union { ushort us[32]; float4 f4[4]; } vals;
    if (zc == 0) {
#pragma unroll
      for (int s = 0; s < 18; ++s) {
        int ch = s / 9, a = s % 9, u = a / 3, v = a % 3;
        vals.us[s] = xs2[((bpy + u) * 18 + bpx + v) * 2 + ch];
      }
#pragma unroll
      for (int d = 0; d < 14; ++d)
        vals.us[18 + d] = f2bf(o1s[(bpy + d / 5) * 20 + bpx + d % 5]);
    } else {
#pragma unroll
      for (int s = 0; s < 11; ++s) {
        int d = 14 + s;
        vals.us[s] = f2bf(o1s[(bpy + d / 5) * 20 + bpx + d % 5]);
      }
#pragma unroll
      for (int s = 11; s < 32; ++s) vals.us[s] = 0;
    }
    __syncthreads();
#pragma unroll
    for (int u = 0; u < 4; ++u)
      *(float4*)(az + tid * 32 + ((u ^ (tid & 3)) << 3)) = vals.f4[u];
    __syncthreads();
    bf16x8 bf[5];
#pragma unroll
    for (int nt = 0; nt < 5; ++nt)
      bf[nt] = *(const bf16x8*)(BwZ + ((zc * 80 + nt * 16 + m) * 32 + q * 8));
#pragma unroll
    for (int mt = 0; mt < 4; ++mt) {
      int px = (((wave << 2) + mt) << 4) + m;
      bf16x8 af = *(const bf16x8*)(az + px * 32 + ((q ^ (px & 3)) << 3));
#pragma unroll
      for (int nt = 0; nt < 5; ++nt)
        acc[mt][nt] = MFMA16(af, bf[nt], acc[mt][nt]);
    }
  }
#pragma unroll 1
  for (int nt = 0; nt < 5; ++nt) {
    __syncthreads();
#pragma unroll
    for (int mt = 0; mt < 4; ++mt) {
      int pxb = (((wave << 2) + mt) << 4);
#pragma unroll
      for (int r = 0; r < 4; ++r)
        st[m * 257 + pxb + q * 4 + r] = acc[mt][nt][r];
    }
    __syncthreads();
#pragma unroll
    for (int kk = 0; kk < 16; ++kk) {
      int o = nt * 16 + kk;
      if (o < 66) {
        float bvv = bias_tot[o];
        outf[((b * 66 + o) * HH + h0 + (tid >> 4)) * WW + w0 + (tid & 15)] =
            st[kk * 257 + tid] + bvv;
      }
    }
  }
}

// ---------------------------------------------------------------------------
// Border fixup (unchanged)
// ---------------------------------------------------------------------------
__global__ __launch_bounds__(256) void k_fix(const float* __restrict__ out1,
                                             const float* __restrict__ T,
                                             const float* __restrict__ TB,
                                             float* __restrict__ outf) {
  int idx = blockIdx.x * 256 + threadIdx.x;
  if (idx >= 8 * 1020 * 66) return;
  int b = idx / (1020 * 66);
  int rem = idx % (1020 * 66);
  int pi = rem / 66, o = rem % 66;
  int ph, pw;
  if (pi < 256)      { ph = 0;        pw = pi; }
  else if (pi < 512) { ph = 255;      pw = pi - 256; }
  else if (pi < 766) { ph = pi - 511; pw = 0; }
  else               { ph = pi - 765; pw = 255; }
  float corr = 0.f;
#pragma unroll
  for (int a = 0; a < 9; ++a) {
    int ua = a / 3, va = a % 3;
    int qh = ph + ua - 1, qw = pw + va - 1;
    if (qh >= 0 && qh < HH && qw >= 0 && qw < WW) continue;
    float s = TB[o * 9 + a];
#pragma unroll
    for (int t2 = 0; t2 < 9; ++t2) {
      int rh = qh + t2 / 3 - 1, rw = qw + t2 % 3 - 1;
      if (rh >= 0 && rh < HH && rw >= 0 && rw < WW)
        s += out1[b * HW + rh * WW + rw] * T[(o * 9 + a) * 9 + t2];
    }
    corr += s;
  }
  outf[((b * 66 + o) * HH + ph) * WW + pw] -= corr;
}

// ---------------------------------------------------------------------------
extern "C" void kernel_launch(void* const* d_in, const int* in_sizes, int n_in,
                              void* d_out, int out_size, void* d_ws, size_t ws_size,
                              hipStream_t stream) {
  const float* x   = (const float*)d_in[0];
  const float* wg  = (const float*)d_in[1];
  const float* p1w = (const float*)d_in[2];
  const float* p1b = (const float*)d_in[3];
  const float* p2w = (const float*)d_in[4];
  const float* p3w = (const float*)d_in[5];
  const float* csw = (const float*)d_in[6];
  const float* csb = (const float*)d_in[7];
  const float* trw = (const float*)d_in[8];
  const float* trb = (const float*)d_in[9];
  const float* fuw = (const float*)d_in[10];
  const float* fub = (const float*)d_in[11];
  float* outf = (float*)d_out;                 // fused: 8*66*256*256
  float* out2 = outf + 34603008;               // ax_out: 8*3*256*256
  char* ws = (char*)d_ws;
  __hip_bfloat16* xg = (__hip_bfloat16*)(ws + OFF_XG);
  float* pp      = (float*)(ws + OFF_PP);
  ushort* Bp     = (ushort*)(ws + OFF_BP);
  ushort* xgn    = (ushort*)(ws + OFF_XGN);
  float* out1    = (float*)(ws + OFF_OUT1);
  float* kernw   = (float*)(ws + OFF_KERN);
  ushort* Bw     = (ushort*)(ws + OFF_BW);
  ushort* BwZ    = (ushort*)(ws + OFF_BWZ);
  float* biasT   = (float*)(ws + OFF_BIAS);
  float* TBp     = (float*)(ws + OFF_TB);
  float* Tp      = (float*)(ws + OFF_T);

  hipLaunchKernelGGL(k_prepA, dim3(460), dim3(256), 0, stream,
                     fuw, trw, trb, p1w, Tp, TBp, Bw, Bp);
  hipLaunchKernelGGL(k_prepB, dim3(21), dim3(256), 0, stream,
                     fuw, fub, Tp, TBp, BwZ, biasT);
  hipLaunchKernelGGL(k_xgauss, dim3(1, 32, 8 * 24), dim3(256), 0, stream, x, wg, xg);
  hipLaunchKernelGGL(k_tr, dim3(8192), dim3(256), 0, stream, (const ushort*)xg, xgn);
  hipLaunchKernelGGL(k_pmm, dim3(16, 16, 8), dim3(256), 0, stream, x, Bp, p1b, pp);
  hipLaunchKernelGGL(k_pred2, dim3(8), dim3(256), 0, stream, pp, p2w, p3w, kernw);
  hipLaunchKernelGGL(k_dyn, dim3(4, 16, 8), dim3(256), 0, stream, x, kernw, out1);
  hipLaunchKernelGGL(k_fmma, dim3(16, 16, 8), dim3(256), 0, stream,
                     xgn, out1, Bw, BwZ, biasT, outf);
  hipLaunchKernelGGL(k_fix, dim3(2104), dim3(256), 0, stream, out1, Tp, TBp, outf);
  hipLaunchKernelGGL(k_ax, dim3(6144), dim3(256), 0, stream, x, csw, csb, out2);
}